// Round 5
// baseline (369.365 us; speedup 1.0000x reference)
//
#include <hip/hip_runtime.h>

#define HDIM 128   // hidden = HEADS*D = 2*64

typedef __attribute__((ext_vector_type(8))) short short8;
typedef __attribute__((ext_vector_type(4))) float float4v;

__device__ __forceinline__ float b2f(unsigned short u){
  return __uint_as_float(((unsigned int)u) << 16);
}
__device__ __forceinline__ unsigned short f2b(float f){
  unsigned int x = __float_as_uint(f);
  x += 0x7fffu + ((x >> 16) & 1u);           // round-to-nearest-even
  return (unsigned short)(x >> 16);
}

#if __has_builtin(__builtin_amdgcn_exp2f)
#define EXPX(x) __builtin_amdgcn_exp2f(x)
#define LOGSCALE 1.4426950408889634f
#else
#define EXPX(x) __expf(x)
#define LOGSCALE 1.f
#endif

// sum over each 8-lane group (dims of one head) — pure-VALU DPP tree, no LDS pipe
__device__ __forceinline__ float dpp_red8(float x){
  x += __int_as_float(__builtin_amdgcn_update_dpp(0, __float_as_int(x), 0xB1, 0xF, 0xF, true));  // quad_perm xor1
  x += __int_as_float(__builtin_amdgcn_update_dpp(0, __float_as_int(x), 0x4E, 0xF, 0xF, true));  // quad_perm xor2
  x += __int_as_float(__builtin_amdgcn_update_dpp(0, __float_as_int(x), 0x141, 0xF, 0xF, true)); // row_half_mirror
  return x;
}

// per-block redundant dtype sniff (reads 4 KB of x; L2-hot after first block)
__device__ __forceinline__ int sniff_block(const unsigned short* __restrict__ x){
  const int tid = threadIdx.x;               // 256 threads
  int cnt = 0, tot = 0;
  for (int i = tid * 2; i < 4096; i += 512){
    float v = fabsf(b2f(x[i]));
    tot++;
    if (v > 1e-4f && v < 50.f) cnt++;
  }
  __shared__ int s_cnt[256], s_tot[256];
  s_cnt[tid] = cnt; s_tot[tid] = tot;
  __syncthreads();
  for (int o = 128; o > 0; o >>= 1){
    if (tid < o){ s_cnt[tid] += s_cnt[tid + o]; s_tot[tid] += s_tot[tid + o]; }
    __syncthreads();
  }
  __shared__ int res;
  if (tid == 0) res = (s_cnt[0] * 2 < s_tot[0]) ? 1 : 0;
  __syncthreads();
  return res;
}

// canonical params layout (ushort offsets into P)
#define P_WPU 0
#define P_WPI 8192
#define P_WL  24576
#define P_WR  90112
#define P_BL  155648
#define P_BR  156160
#define P_ATT 156672
#define P_BIA 157184
#define P_BPU 157696
#define P_BPI 157824
#define P_TOT 157952

struct CvtArgs { const void* src[10]; int len[10]; const unsigned short* xsniff; };

// cvt + inline sniff + zero scratch (curs, hists+tickets) + publish flag — kills 3 dispatches
__global__ void cvt_all_kernel(CvtArgs args, unsigned short* __restrict__ P,
                               int* __restrict__ flag,
                               int* __restrict__ zero1, int nz1,
                               int* __restrict__ zero2, int nz2){
  const int f32 = sniff_block(args.xsniff);
  int t = blockIdx.x * 256 + threadIdx.x;
  if (t < nz1) zero1[t] = 0;
  if (t < nz2) zero2[t] = 0;
  if (t == 0) flag[0] = f32;
  if (t >= P_TOT) return;
  int local = t;
  int i = 0;
  while (local >= args.len[i]){ local -= args.len[i]; i++; }
  if (f32) P[t] = f2b(((const float*)args.src[i])[local]);
  else     P[t] = ((const unsigned short*)args.src[i])[local];
}

// ---------------- prep: compose layer-0 weights  Wc = Wp @ W  (+ bp @ W + b)
__global__ void prep_weights_kernel(const unsigned short* __restrict__ P,
                                    unsigned short* __restrict__ Wc)
{
  const int t = blockIdx.x * 256 + threadIdx.x;
  if (t >= 49664) return;
  const unsigned short* Wl = P + P_WL;
  const unsigned short* Wr = P + P_WR;
  const unsigned short* Bm[4] = { Wl, Wr + 16384, Wl + 16384, Wr };
  const unsigned short* Av[4] = { P + P_WPU, P + P_WPU, P + P_WPI, P + P_WPI };
  const unsigned short* bv[4] = { P + P_BPU, P + P_BPU, P + P_BPI, P + P_BPI };
  const unsigned short* bo[4] = { P + P_BL, P + P_BR + 128, P + P_BL + 128, P + P_BR };
  if (t < 49152){
    int job, base;
    if (t < 8192)       { job = 0; base = 0; }
    else if (t < 16384) { job = 1; base = 8192; }
    else if (t < 32768) { job = 2; base = 16384; }
    else                { job = 3; base = 32768; }
    const int local = t - base;
    const int k = local >> 7, n = local & 127;
    const unsigned short* A = Av[job] + (size_t)k * 128;
    const unsigned short* B = Bm[job];
    float s = 0.f;
    #pragma unroll 4
    for (int h = 0; h < 128; h++) s = fmaf(b2f(A[h]), b2f(B[h * 128 + n]), s);
    Wc[t] = f2b(s);
  } else {
    const int local = t - 49152;
    const int job = local >> 7, n = local & 127;
    const unsigned short* B = Bm[job];
    float s = b2f(bo[job][n]);
    for (int h = 0; h < 128; h++) s = fmaf(b2f(bv[job][h]), b2f(B[h * 128 + n]), s);
    Wc[t] = f2b(s);
  }
}

// ---------------- permute all 4 concat weights into B-fragment order + concat biases (merged)
struct PermBiasArgs { const unsigned short* W0[4]; const unsigned short* W1[4];
                      int KS[4]; int base[4]; int n[4];
                      const unsigned short* blo[4]; const unsigned short* bhi[4]; };
__global__ void permute_bias_kernel(PermBiasArgs pa, unsigned short* __restrict__ dst,
                                    unsigned short* __restrict__ dstB){
  int t = blockIdx.x * 256 + threadIdx.x;
  if (t >= 114688){
    int u = t - 114688;
    if (u < 1024){
      int set = u >> 8, c = u & 255;
      dstB[u] = (c < 128) ? pa.blo[set][c] : pa.bhi[set][c - 128];
    }
    return;
  }
  int job = 0;
  while (job < 4 && t >= pa.base[job] + pa.n[job]) job++;
  if (job >= 4) return;
  int local = t - pa.base[job];
  int KS = pa.KS[job];
  int j = local & 7, rest = local >> 3;
  int l = rest & 63; rest >>= 6;
  int ks = rest % KS, tile = rest / KS;
  int k = ks * 32 + (l >> 4) * 8 + j;
  int c = tile * 16 + (l & 15);
  dst[t] = (c < 128) ? pa.W0[job][k * 128 + c] : pa.W1[job][k * 128 + (c - 128)];
}

// ---------------- MFMA linear body + dual-range kernel (NU and NI jobs in one dispatch)
template<int K>
__device__ __forceinline__ void linear_body(const void* __restrict__ Xv, int xstride,
                                            bool f32,
                                            const unsigned short* __restrict__ Bp,
                                            const unsigned short* __restrict__ bias,
                                            unsigned short* __restrict__ Y, int M, int bx)
{
  constexpr int KS = K / 32;
  const int wave = threadIdx.x >> 6, lane = threadIdx.x & 63;
  const int quad = lane >> 4, l16 = lane & 15;
  const int row0 = bx * 64;

  float4v acc[4][4];
  const float4v z = {0.f, 0.f, 0.f, 0.f};
  #pragma unroll
  for (int i = 0; i < 4; i++)
    #pragma unroll
    for (int j = 0; j < 4; j++) acc[i][j] = z;

  for (int ks = 0; ks < KS; ks++){
    const int col = ks * 32 + quad * 8;
    short8 a[4];
    #pragma unroll
    for (int mt = 0; mt < 4; mt++){
      int r = row0 + mt * 16 + l16; if (r >= M) r = M - 1;
      if (f32){
        const float* p = (const float*)Xv + (size_t)r * xstride + col;
        short8 tmp;
        #pragma unroll
        for (int j = 0; j < 8; j++) tmp[j] = (short)f2b(p[j]);
        a[mt] = tmp;
      } else {
        a[mt] = *(const short8*)((const unsigned short*)Xv + (size_t)r * xstride + col);
      }
    }
    short8 b[4];
    #pragma unroll
    for (int ntl = 0; ntl < 4; ntl++){
      const int t = wave * 4 + ntl;
      b[ntl] = *(const short8*)(Bp + ((size_t)(t * KS + ks) * 64 + lane) * 8);
    }
    #pragma unroll
    for (int mt = 0; mt < 4; mt++)
      #pragma unroll
      for (int ntl = 0; ntl < 4; ntl++)
        acc[mt][ntl] = __builtin_amdgcn_mfma_f32_16x16x32_bf16(a[mt], b[ntl], acc[mt][ntl], 0, 0, 0);
  }

  #pragma unroll
  for (int mt = 0; mt < 4; mt++){
    #pragma unroll
    for (int ntl = 0; ntl < 4; ntl++){
      const int t = wave * 4 + ntl;
      const int colb = t * 16 + l16;
      const float bb = b2f(bias[colb]);
      #pragma unroll
      for (int r = 0; r < 4; r++){
        const int row = row0 + mt * 16 + quad * 4 + r;
        if (row < M) Y[(size_t)row * 256 + colb] = f2b(acc[mt][ntl][r] + bb);
      }
    }
  }
}

template<int KA, int KB>
__launch_bounds__(256)
__global__ void linear_both_kernel(const void* __restrict__ XA, int sA,
                                   const unsigned short* __restrict__ BpA,
                                   const unsigned short* __restrict__ biasA,
                                   unsigned short* __restrict__ YA, int MA, int gA,
                                   const void* __restrict__ XB, int sB,
                                   const unsigned short* __restrict__ BpB,
                                   const unsigned short* __restrict__ biasB,
                                   unsigned short* __restrict__ YB, int MB,
                                   const int* __restrict__ flag, int use_flag)
{
  const bool f32 = use_flag && (*flag != 0);
  if ((int)blockIdx.x < gA) linear_body<KA>(XA, sA, f32, BpA, biasA, YA, MA, blockIdx.x);
  else                      linear_body<KB>(XB, sB, f32, BpB, biasB, YB, MB, blockIdx.x - gA);
}

// ================= CSR build =================
__global__ void count_both_kernel(const int* __restrict__ esrc, const int* __restrict__ edst,
                                  int* __restrict__ degU, int* __restrict__ degI, int E){
  int t = blockIdx.x * 256 + threadIdx.x;
  if (t >= E) return;
  atomicAdd(&degI[edst[t]], 1);
  atomicAdd(&degU[esrc[t]], 1);
}

// merged: per-block scan (+ last-block top scan) || degree histogram (+ last-block suffix scan)
__global__ void scan_hist_fused_kernel(const int* __restrict__ degI, const int* __restrict__ degU,
                                       int* __restrict__ rpI, int* __restrict__ rpU,
                                       int* __restrict__ blkI, int* __restrict__ blkU,
                                       int* __restrict__ histI, int* __restrict__ histU,
                                       int* __restrict__ tick,
                                       int NI, int NU, int BI, int BU, int BI2, int BU2){
  const int tid = threadIdx.x;
  const int b = blockIdx.x;
  const int nscan = BI + BU;
  if (b < nscan){
    __shared__ int s[256];
    const int* deg; int* rowptr; int* blksum; int Nd; int bb;
    if (b < BI){ deg = degI; rowptr = rpI; blksum = blkI; Nd = NI; bb = b; }
    else       { deg = degU; rowptr = rpU; blksum = blkU; Nd = NU; bb = b - BI; }
    const int base = bb * 2048 + tid * 8;
    int v[8]; int tot = 0;
    #pragma unroll
    for (int j = 0; j < 8; j++){
      int idx = base + j;
      v[j] = (idx < Nd) ? deg[idx] : 0;
      tot += v[j];
    }
    s[tid] = tot;
    __syncthreads();
    for (int off = 1; off < 256; off <<= 1){
      int add = (tid >= off) ? s[tid - off] : 0;
      __syncthreads();
      s[tid] += add;
      __syncthreads();
    }
    int run = s[tid] - tot;
    #pragma unroll
    for (int j = 0; j < 8; j++){
      int idx = base + j;
      if (idx < Nd) rowptr[idx] = run;
      run += v[j];
    }
    if (tid == 255) blksum[bb] = s[255];
    // last scan-block performs the top-level exclusive scan of blkI/blkU inline
    __threadfence();
    __shared__ int lastS;
    if (tid == 0) lastS = (atomicAdd(&tick[0], 1) == nscan - 1) ? 1 : 0;
    __syncthreads();
    if (lastS && tid < 128){
      __threadfence();
      int* blk = (tid < 64) ? blkI : blkU;
      const int B = (tid < 64) ? BI : BU;
      const int lane = tid & 63;
      int v2 = (lane < B) ? blk[lane] : 0;
      const int orig = v2;
      #pragma unroll
      for (int off = 1; off < 64; off <<= 1){
        int u = __shfl_up(v2, off, 64);
        if (lane >= off) v2 += u;
      }
      if (lane < B) blk[lane] = v2 - orig;
    }
  } else {
    // degree histogram part (reads raw deg arrays)
    __shared__ int h2[64];
    if (tid < 64) h2[tid] = 0;
    __syncthreads();
    const int bb = b - nscan;
    const int* deg; int* gh; int base; int N;
    if (bb < BI2){ deg = degI; gh = histI; base = bb * 256; N = NI; }
    else         { deg = degU; gh = histU; base = (bb - BI2) * 256; N = NU; }
    const int n = base + tid;
    if (n < N) atomicAdd(&h2[min(deg[n], 63)], 1);
    __syncthreads();
    if (tid < 64 && h2[tid]) atomicAdd(&gh[tid], h2[tid]);
    // last hist-block performs the suffix (descending) scan inline
    __threadfence();
    __shared__ int lastH;
    if (tid == 0) lastH = (atomicAdd(&tick[1], 1) == (BI2 + BU2) - 1) ? 1 : 0;
    __syncthreads();
    if (lastH && tid < 128){
      __threadfence();
      const int lane = tid & 63;
      int* hh = (tid < 64) ? histI : histU;
      int v = hh[lane];
      int x = v;
      #pragma unroll
      for (int off = 1; off < 64; off <<= 1){
        int u = __shfl_down(x, off, 64);
        x += (lane + off < 64) ? u : 0;
      }
      hh[lane] = x - v;
    }
  }
}

__global__ void scan_add2_kernel(int* __restrict__ rpI, int* __restrict__ rpU,
                                 const int* __restrict__ blkI, const int* __restrict__ blkU,
                                 int* __restrict__ curI, int* __restrict__ curU,
                                 int NI, int NU, int BI, int E){
  const int b = blockIdx.x;
  int* rowptr; const int* blksum; int* curs; int Nd; int bb;
  if (b < BI){ rowptr = rpI; blksum = blkI; curs = curI; Nd = NI; bb = b; }
  else       { rowptr = rpU; blksum = blkU; curs = curU; Nd = NU; bb = b - BI; }
  const int base = bb * 2048 + threadIdx.x * 8;
  const int add = blksum[bb];
  #pragma unroll
  for (int j = 0; j < 8; j++){
    int idx = base + j;
    if (idx < Nd){ int v = rowptr[idx] + add; rowptr[idx] = v; curs[idx] = v; }
    else if (idx == Nd) rowptr[idx] = E;
  }
}

// merged: perm scatter (counting-sort placement) + edge scatter, one dispatch
__global__ void scatter_all_kernel(const int* __restrict__ esrc, const int* __restrict__ edst,
                                   int* __restrict__ curI, int* __restrict__ curU,
                                   int* __restrict__ srcI, int* __restrict__ srcU,
                                   const int* __restrict__ rpI, const int* __restrict__ rpU,
                                   int* __restrict__ histI, int* __restrict__ histU,
                                   int* __restrict__ permI, int* __restrict__ permU,
                                   int NI, int NU, int E, int BI2, int BU2){
  const int tid = threadIdx.x;
  const int b = blockIdx.x;
  const int BP = BI2 + BU2;
  if (b < BP){
    __shared__ int h[64];
    __shared__ int cur[64];
    if (tid < 64) h[tid] = 0;
    __syncthreads();
    const int* rp; int* gh; int* perm; int base; int N;
    if (b < BI2){ rp = rpI; gh = histI; perm = permI; base = b * 256; N = NI; }
    else        { rp = rpU; gh = histU; perm = permU; base = (b - BI2) * 256; N = NU; }
    const int n = base + tid;
    int bk = -1;
    if (n < N){ int d = rp[n + 1] - rp[n]; bk = min(d, 63); atomicAdd(&h[bk], 1); }
    __syncthreads();
    if (tid < 64) cur[tid] = h[tid] ? atomicAdd(&gh[tid], h[tid]) : 0;
    __syncthreads();
    if (n < N){ int r = atomicAdd(&cur[bk], 1); perm[r] = n; }
  } else {
    int t = (b - BP) * 256 + tid;
    if (t < E){
      int d = edst[t];
      int pos = atomicAdd(&curI[d], 1);
      srcI[pos] = esrc[t];
    } else if (t < 2 * E){
      int tt = t - E;
      int d = esrc[tt];
      int pos = atomicAdd(&curU[d], 1);
      srcU[pos] = edst[tt];
    }
  }
}

// ================= fused GATv2: 4 nodes/wave (16 lanes each), degree-sorted =================
// R1-exact structure: single online-softmax state, 1 edge/iter, depth-1.5 prefetch, VGPR ~24.
struct GatRel {
  const unsigned short* zlrS; // source features [Ns][256] bf16 (xl at +0)
  const unsigned short* zlrD; // dest features   [Nd][256] bf16 (xr at +128)
  const int* rowptr;
  const int* srcArr;
  const int* perm;            // degree-sorted node ids (descending)
  const unsigned short* att;  // [128]
  const unsigned short* bias; // [128]
  void* out;
  unsigned long long elem_off;
  int Nd;
  int nw;                     // ceil(Nd/4)
};

__launch_bounds__(256)
__global__ void fused_gat_sorted_kernel(GatRel A, GatRel B, int do_relu,
                                        const int* __restrict__ flag, int final_store)
{
  const int wave = threadIdx.x >> 6;
  const int lane = threadIdx.x & 63;
  const int ql = lane & 15;
  const int quad = lane >> 4;
  int gw = blockIdx.x * 4 + wave;
  GatRel R;
  if (gw < A.nw) R = A;
  else {
    gw -= A.nw;
    if (gw >= B.nw) return;
    R = B;
  }

  const int rank = gw * 4 + quad;
  const bool vnode = rank < R.Nd;
  int d = 0;
  if (vnode) d = R.perm[rank];
  int beg = 0, end = 0;
  if (vnode){ beg = R.rowptr[d]; end = R.rowptr[d + 1]; }
  int md = end - beg;
  md = max(md, __shfl_xor(md, 16, 64));
  md = max(md, __shfl_xor(md, 32, 64));

  const uint4* zlS4 = (const uint4*)R.zlrS;
  // xr row of dest node: dims [8*ql, 8*ql+8)
  uint4 rv = ((const uint4*)R.zlrD)[(size_t)d * 32 + 16 + ql];
  float r[8], a[8];
  {
    const unsigned int* rp = (const unsigned int*)&rv;
    #pragma unroll
    for (int j = 0; j < 4; j++){
      r[2*j]   = __uint_as_float(rp[j] << 16);
      r[2*j+1] = __uint_as_float(rp[j] & 0xffff0000u);
    }
  }
  uint4 av = ((const uint4*)R.att)[ql];
  {
    const unsigned int* ap = (const unsigned int*)&av;
    #pragma unroll
    for (int j = 0; j < 4; j++){
      a[2*j]   = __uint_as_float(ap[j] << 16) * LOGSCALE;
      a[2*j+1] = __uint_as_float(ap[j] & 0xffff0000u) * LOGSCALE;
    }
  }

  float m = -1e30f, s = 0.f;
  float acc[8];
  #pragma unroll
  for (int j = 0; j < 8; j++) acc[j] = 0.f;

  if (md > 0){
    const int* sA = R.srcArr;
    int i1 = 0, i2 = 0;
    if (beg < end)     i1 = sA[beg];
    if (beg + 1 < end) i2 = sA[beg + 1];
    uint4 g0 = zlS4[(size_t)i1 * 32 + ql];

    for (int it = 0; it < md; it++){
      uint4 g1 = zlS4[(size_t)i2 * 32 + ql];     // prefetch row for it+1
      int i3 = 0;
      { int ee = beg + it + 2; if (ee < end) i3 = sA[ee]; }   // prefetch idx for it+2
      const bool valid = (beg + it) < end;

      float x[8];
      const unsigned int* gp = (const unsigned int*)&g0;
      #pragma unroll
      for (int j = 0; j < 4; j++){
        x[2*j]   = __uint_as_float(gp[j] << 16);
        x[2*j+1] = __uint_as_float(gp[j] & 0xffff0000u);
      }
      float p = 0.f;
      #pragma unroll
      for (int j = 0; j < 8; j++){
        float t = x[j] + r[j];
        t = fmaxf(t, 0.2f * t);
        p = fmaf(a[j], t, p);
      }
      p = dpp_red8(p);
      const float pv = valid ? p : -1e30f;

      if (__builtin_expect(__any(pv > m + 8.f), 0)){
        const float mn = fmaxf(m, pv);
        const float scO = EXPX(m - mn);
        const float qv = valid ? EXPX(pv - mn) : 0.f;
        s = fmaf(s, scO, qv);
        #pragma unroll
        for (int j = 0; j < 8; j++) acc[j] = fmaf(acc[j], scO, x[j] * qv);
        m = mn;
      } else {
        const float qv = valid ? EXPX(pv - m) : 0.f;
        s += qv;
        #pragma unroll
        for (int j = 0; j < 8; j++) acc[j] = fmaf(x[j], qv, acc[j]);
      }
      g0 = g1; i2 = i3;
    }
  }

  const float inv = 1.f / (s + 1e-16f);
  uint4 bv = ((const uint4*)R.bias)[ql];
  float o[8];
  {
    const unsigned int* bp = (const unsigned int*)&bv;
    #pragma unroll
    for (int j = 0; j < 4; j++){
      o[2*j]   = fmaf(acc[2*j],   inv, __uint_as_float(bp[j] << 16));
      o[2*j+1] = fmaf(acc[2*j+1], inv, __uint_as_float(bp[j] & 0xffff0000u));
    }
  }
  if (do_relu){
    #pragma unroll
    for (int j = 0; j < 8; j++) o[j] = fmaxf(o[j], 0.f);
  }
  if (!vnode) return;
  const size_t eidx = (size_t)R.elem_off + (size_t)d * HDIM + 8 * ql;
  if (final_store && (*flag != 0)){
    float4 f0 = {o[0], o[1], o[2], o[3]};
    float4 f1 = {o[4], o[5], o[6], o[7]};
    float4* op = (float4*)R.out;
    op[eidx >> 2] = f0;
    op[(eidx >> 2) + 1] = f1;
  } else {
    uint4 w;
    unsigned int* wp = (unsigned int*)&w;
    #pragma unroll
    for (int j = 0; j < 4; j++)
      wp[j] = (unsigned int)f2b(o[2*j]) | ((unsigned int)f2b(o[2*j+1]) << 16);
    ((uint4*)R.out)[eidx >> 3] = w;
  }
}

extern "C" void kernel_launch(void* const* d_in, const int* in_sizes, int n_in,
                              void* d_out, int out_size, void* d_ws, size_t ws_size,
                              hipStream_t stream)
{
  const int* esrc = (const int*)d_in[12];
  const int* edst = (const int*)d_in[13];

  const int NU = in_sizes[0] / 64;    // 100000
  const int NI = in_sizes[1] / 128;   // 20000
  const int E  = in_sizes[12];        // 250000
  const size_t fu = (size_t)NU * HDIM, fi = (size_t)NI * HDIM;

  // ---- workspace carve, 256B-aligned regions
  char* w = (char*)d_ws;
  auto carve = [&](size_t bytes){ char* p = w; w += (bytes + 255) & ~(size_t)255; return p; };
  int* flag = (int*)carve(4);
  unsigned short* Wc = (unsigned short*)carve(49664 * 2);
  unsigned short* P  = (unsigned short*)carve((size_t)P_TOT * 2);
  unsigned short* Bp = (unsigned short*)carve(114688 * 2);
  unsigned short* Bc = (unsigned short*)carve(1024 * 2);
  int* rowptrI = (int*)carve(((size_t)NI + 1) * 4);
  int* rowptrU = (int*)carve(((size_t)NU + 1) * 4);
  int* curs    = (int*)carve(((size_t)NI + NU) * 4);
  int* cursI = curs;
  int* cursU = curs + NI;
  int* blkI = (int*)carve(64 * 4);
  int* blkU = (int*)carve(64 * 4);
  int* hists = (int*)carve(144 * 4);       // histI[64] | histU[64] | tick[2]
  int* histI = hists;
  int* histU = hists + 64;
  int* tick  = hists + 128;
  int* permI = (int*)carve((size_t)NI * 4);
  int* permU = (int*)carve((size_t)NU * 4);
  int* srcI  = (int*)carve((size_t)E * 4);
  int* srcU  = (int*)carve((size_t)E * 4);
  unsigned short* zlrU = (unsigned short*)carve((size_t)NU * 256 * 2);  // [NU][xl|xr]
  unsigned short* zlrI = (unsigned short*)carve((size_t)NI * 256 * 2);  // [NI][xl|xr]
  (void)ws_size; (void)n_in; (void)out_size; (void)fi;

  unsigned short* stage_zu = (unsigned short*)d_out;          // layer-0 bf16 staging
  unsigned short* stage_zi = (unsigned short*)d_out + fu;
  (void)stage_zi; (void)tick;

  // ---- 1: cvt (+sniff +zero curs/hists/tick +publish flag)
  CvtArgs ca;
  const int srcIdx[10] = {2, 4, 6, 8, 7, 9, 10, 11, 3, 5};
  const int lens[10] = {8192, 16384, 65536, 65536, 512, 512, 512, 512, 128, 128};
  for (int i = 0; i < 10; i++){ ca.src[i] = d_in[srcIdx[i]]; ca.len[i] = lens[i]; }
  ca.xsniff = (const unsigned short*)d_in[0];
  cvt_all_kernel<<<(P_TOT + 255) / 256, 256, 0, stream>>>(ca, P, flag,
                                                          curs, NI + NU, hists, 130);
  // ---- 2: prep
  prep_weights_kernel<<<(49664 + 255) / 256, 256, 0, stream>>>(P, Wc);

  const unsigned short* cWlU0 = Wc;                 // [64,128]
  const unsigned short* cWrU1 = Wc + 8192;          // [64,128]
  const unsigned short* cWlI1 = Wc + 16384;         // [128,128]
  const unsigned short* cWrI0 = Wc + 32768;         // [128,128]

  // ---- 3: permute + bias concat (merged)
  PermBiasArgs pa;
  pa.W0[0] = cWlU0;                 pa.W1[0] = cWrU1;                 pa.KS[0] = 2; pa.base[0] = 0;     pa.n[0] = 16384;
  pa.W0[1] = cWlI1;                 pa.W1[1] = cWrI0;                 pa.KS[1] = 4; pa.base[1] = 16384; pa.n[1] = 32768;
  pa.W0[2] = P + P_WL + 2 * 16384;  pa.W1[2] = P + P_WR + 3 * 16384;  pa.KS[2] = 4; pa.base[2] = 49152; pa.n[2] = 32768;
  pa.W0[3] = P + P_WL + 3 * 16384;  pa.W1[3] = P + P_WR + 2 * 16384;  pa.KS[3] = 4; pa.base[3] = 81920; pa.n[3] = 32768;
  pa.blo[0] = Wc + 49152;         pa.bhi[0] = Wc + 49152 + 128;
  pa.blo[1] = Wc + 49152 + 256;   pa.bhi[1] = Wc + 49152 + 384;
  pa.blo[2] = P + P_BL + 256;     pa.bhi[2] = P + P_BR + 384;
  pa.blo[3] = P + P_BL + 384;     pa.bhi[3] = P + P_BR + 256;
  permute_bias_kernel<<<(114688 + 1024 + 255) / 256, 256, 0, stream>>>(pa, Bp, Bc);
  unsigned short* BpU0 = Bp;
  unsigned short* BpI0 = Bp + 16384;
  unsigned short* BpU1 = Bp + 49152;
  unsigned short* BpI1 = Bp + 81920;

  // ---- 4-7: CSR build + degree sort (4 dispatches)
  const int BI = (NI + 2047) / 2048, BU = (NU + 2047) / 2048;
  const int BI2 = (NI + 255) / 256, BU2 = (NU + 255) / 256;
  count_both_kernel<<<(E + 255) / 256, 256, 0, stream>>>(esrc, edst, cursU, cursI, E);
  scan_hist_fused_kernel<<<BI + BU + BI2 + BU2, 256, 0, stream>>>(
      cursI, cursU, rowptrI, rowptrU, blkI, blkU, histI, histU, tick,
      NI, NU, BI, BU, BI2, BU2);
  scan_add2_kernel<<<BI + BU, 256, 0, stream>>>(rowptrI, rowptrU, blkI, blkU, cursI, cursU, NI, NU, BI, E);
  scatter_all_kernel<<<BI2 + BU2 + (2 * E + 255) / 256, 256, 0, stream>>>(
      esrc, edst, cursI, cursU, srcI, srcU, rowptrI, rowptrU,
      histI, histU, permI, permU, NI, NU, E, BI2, BU2);

  const int gMU = (NU + 63) / 64, gMI = (NI + 63) / 64;
  const int nwA = (NI + 3) / 4, nwB = (NU + 3) / 4;
  const int gGat = (nwA + nwB + 3) / 4;   // 256-thread blocks = 4 waves

  for (int l = 0; l < 2; l++){
    if (l == 0){
      linear_both_kernel<64, 128><<<gMU + gMI, 256, 0, stream>>>(
          d_in[0], 64, BpU0, Bc, zlrU, NU, gMU,
          d_in[1], 128, BpI0, Bc + 256, zlrI, NI, flag, 1);
    } else {
      linear_both_kernel<128, 128><<<gMU + gMI, 256, 0, stream>>>(
          stage_zu, 128, BpU1, Bc + 512, zlrU, NU, gMU,
          stage_zi, 128, BpI1, Bc + 768, zlrI, NI, flag, 0);
    }
    const int relu = (l == 0);
    const int final_store = (l == 1);

    GatRel A, B;
    // rel 0: user -> item (dst=item)
    A.zlrS = zlrU; A.zlrD = zlrI; A.rowptr = rowptrI; A.srcArr = srcI; A.perm = permI;
    A.att  = P + P_ATT + (l * 2 + 0) * HDIM;
    A.bias = P + P_BIA + (l * 2 + 0) * HDIM;
    A.out = final_store ? d_out : (void*)stage_zu; A.elem_off = fu; A.Nd = NI; A.nw = nwA;
    // rel 1: item -> user (dst=user)
    B.zlrS = zlrI; B.zlrD = zlrU; B.rowptr = rowptrU; B.srcArr = srcU; B.perm = permU;
    B.att  = P + P_ATT + (l * 2 + 1) * HDIM;
    B.bias = P + P_BIA + (l * 2 + 1) * HDIM;
    B.out = final_store ? d_out : (void*)stage_zu; B.elem_off = 0; B.Nd = NU; B.nw = nwB;

    fused_gat_sorted_kernel<<<gGat, 256, 0, stream>>>(A, B, relu, flag, final_store);
  }
}

// Round 6
// 325.839 us; speedup vs baseline: 1.1336x; 1.1336x over previous
//
#include <hip/hip_runtime.h>

#define HDIM 128   // hidden = HEADS*D = 2*64

typedef __attribute__((ext_vector_type(8))) short short8;
typedef __attribute__((ext_vector_type(4))) float float4v;

__device__ __forceinline__ float b2f(unsigned short u){
  return __uint_as_float(((unsigned int)u) << 16);
}
__device__ __forceinline__ unsigned short f2b(float f){
  unsigned int x = __float_as_uint(f);
  x += 0x7fffu + ((x >> 16) & 1u);           // round-to-nearest-even
  return (unsigned short)(x >> 16);
}

#if __has_builtin(__builtin_amdgcn_exp2f)
#define EXPX(x) __builtin_amdgcn_exp2f(x)
#define LOGSCALE 1.4426950408889634f
#else
#define EXPX(x) __expf(x)
#define LOGSCALE 1.f
#endif

// sum over each 8-lane group (dims of one head) — pure-VALU DPP tree, no LDS pipe
__device__ __forceinline__ float dpp_red8(float x){
  x += __int_as_float(__builtin_amdgcn_update_dpp(0, __float_as_int(x), 0xB1, 0xF, 0xF, true));  // quad_perm xor1
  x += __int_as_float(__builtin_amdgcn_update_dpp(0, __float_as_int(x), 0x4E, 0xF, 0xF, true));  // quad_perm xor2
  x += __int_as_float(__builtin_amdgcn_update_dpp(0, __float_as_int(x), 0x141, 0xF, 0xF, true)); // row_half_mirror
  return x;
}

// per-block redundant dtype sniff (reads 4 KB of x; L2-hot after first block)
__device__ __forceinline__ int sniff_block(const unsigned short* __restrict__ x){
  const int tid = threadIdx.x;               // 256 threads
  int cnt = 0, tot = 0;
  for (int i = tid * 2; i < 4096; i += 512){
    float v = fabsf(b2f(x[i]));
    tot++;
    if (v > 1e-4f && v < 50.f) cnt++;
  }
  __shared__ int s_cnt[256], s_tot[256];
  s_cnt[tid] = cnt; s_tot[tid] = tot;
  __syncthreads();
  for (int o = 128; o > 0; o >>= 1){
    if (tid < o){ s_cnt[tid] += s_cnt[tid + o]; s_tot[tid] += s_tot[tid + o]; }
    __syncthreads();
  }
  __shared__ int res;
  if (tid == 0) res = (s_cnt[0] * 2 < s_tot[0]) ? 1 : 0;
  __syncthreads();
  return res;
}

// canonical params layout (ushort offsets into P)
#define P_WPU 0
#define P_WPI 8192
#define P_WL  24576
#define P_WR  90112
#define P_BL  155648
#define P_BR  156160
#define P_ATT 156672
#define P_BIA 157184
#define P_BPU 157696
#define P_BPI 157824
#define P_TOT 157952

struct CvtArgs { const void* src[10]; int len[10]; const unsigned short* xsniff; };

// cvt + inline sniff + zero scratch (curs, hists) + publish flag
__global__ void cvt_all_kernel(CvtArgs args, unsigned short* __restrict__ P,
                               int* __restrict__ flag,
                               int* __restrict__ zero1, int nz1,
                               int* __restrict__ zero2, int nz2){
  const int f32 = sniff_block(args.xsniff);
  int t = blockIdx.x * 256 + threadIdx.x;
  if (t < nz1) zero1[t] = 0;
  if (t < nz2) zero2[t] = 0;
  if (t == 0) flag[0] = f32;
  if (t >= P_TOT) return;
  int local = t;
  int i = 0;
  while (local >= args.len[i]){ local -= args.len[i]; i++; }
  if (f32) P[t] = f2b(((const float*)args.src[i])[local]);
  else     P[t] = ((const unsigned short*)args.src[i])[local];
}

// ---------------- prep: compose layer-0 weights  Wc = Wp @ W  (+ bp @ W + b)
__global__ void prep_weights_kernel(const unsigned short* __restrict__ P,
                                    unsigned short* __restrict__ Wc)
{
  const int t = blockIdx.x * 256 + threadIdx.x;
  if (t >= 49664) return;
  const unsigned short* Wl = P + P_WL;
  const unsigned short* Wr = P + P_WR;
  const unsigned short* Bm[4] = { Wl, Wr + 16384, Wl + 16384, Wr };
  const unsigned short* Av[4] = { P + P_WPU, P + P_WPU, P + P_WPI, P + P_WPI };
  const unsigned short* bv[4] = { P + P_BPU, P + P_BPU, P + P_BPI, P + P_BPI };
  const unsigned short* bo[4] = { P + P_BL, P + P_BR + 128, P + P_BL + 128, P + P_BR };
  if (t < 49152){
    int job, base;
    if (t < 8192)       { job = 0; base = 0; }
    else if (t < 16384) { job = 1; base = 8192; }
    else if (t < 32768) { job = 2; base = 16384; }
    else                { job = 3; base = 32768; }
    const int local = t - base;
    const int k = local >> 7, n = local & 127;
    const unsigned short* A = Av[job] + (size_t)k * 128;
    const unsigned short* B = Bm[job];
    float s = 0.f;
    #pragma unroll 4
    for (int h = 0; h < 128; h++) s = fmaf(b2f(A[h]), b2f(B[h * 128 + n]), s);
    Wc[t] = f2b(s);
  } else {
    const int local = t - 49152;
    const int job = local >> 7, n = local & 127;
    const unsigned short* B = Bm[job];
    float s = b2f(bo[job][n]);
    for (int h = 0; h < 128; h++) s = fmaf(b2f(bv[job][h]), b2f(B[h * 128 + n]), s);
    Wc[t] = f2b(s);
  }
}

// ---------------- permute all 4 concat weights into B-fragment order + concat biases (merged)
struct PermBiasArgs { const unsigned short* W0[4]; const unsigned short* W1[4];
                      int KS[4]; int base[4]; int n[4];
                      const unsigned short* blo[4]; const unsigned short* bhi[4]; };
__global__ void permute_bias_kernel(PermBiasArgs pa, unsigned short* __restrict__ dst,
                                    unsigned short* __restrict__ dstB){
  int t = blockIdx.x * 256 + threadIdx.x;
  if (t >= 114688){
    int u = t - 114688;
    if (u < 1024){
      int set = u >> 8, c = u & 255;
      dstB[u] = (c < 128) ? pa.blo[set][c] : pa.bhi[set][c - 128];
    }
    return;
  }
  int job = 0;
  while (job < 4 && t >= pa.base[job] + pa.n[job]) job++;
  if (job >= 4) return;
  int local = t - pa.base[job];
  int KS = pa.KS[job];
  int j = local & 7, rest = local >> 3;
  int l = rest & 63; rest >>= 6;
  int ks = rest % KS, tile = rest / KS;
  int k = ks * 32 + (l >> 4) * 8 + j;
  int c = tile * 16 + (l & 15);
  dst[t] = (c < 128) ? pa.W0[job][k * 128 + c] : pa.W1[job][k * 128 + (c - 128)];
}

// ---------------- MFMA linear body + dual-range kernel (NU and NI jobs in one dispatch)
template<int K>
__device__ __forceinline__ void linear_body(const void* __restrict__ Xv, int xstride,
                                            bool f32,
                                            const unsigned short* __restrict__ Bp,
                                            const unsigned short* __restrict__ bias,
                                            unsigned short* __restrict__ Y, int M, int bx)
{
  constexpr int KS = K / 32;
  const int wave = threadIdx.x >> 6, lane = threadIdx.x & 63;
  const int quad = lane >> 4, l16 = lane & 15;
  const int row0 = bx * 64;

  float4v acc[4][4];
  const float4v z = {0.f, 0.f, 0.f, 0.f};
  #pragma unroll
  for (int i = 0; i < 4; i++)
    #pragma unroll
    for (int j = 0; j < 4; j++) acc[i][j] = z;

  for (int ks = 0; ks < KS; ks++){
    const int col = ks * 32 + quad * 8;
    short8 a[4];
    #pragma unroll
    for (int mt = 0; mt < 4; mt++){
      int r = row0 + mt * 16 + l16; if (r >= M) r = M - 1;
      if (f32){
        const float* p = (const float*)Xv + (size_t)r * xstride + col;
        short8 tmp;
        #pragma unroll
        for (int j = 0; j < 8; j++) tmp[j] = (short)f2b(p[j]);
        a[mt] = tmp;
      } else {
        a[mt] = *(const short8*)((const unsigned short*)Xv + (size_t)r * xstride + col);
      }
    }
    short8 b[4];
    #pragma unroll
    for (int ntl = 0; ntl < 4; ntl++){
      const int t = wave * 4 + ntl;
      b[ntl] = *(const short8*)(Bp + ((size_t)(t * KS + ks) * 64 + lane) * 8);
    }
    #pragma unroll
    for (int mt = 0; mt < 4; mt++)
      #pragma unroll
      for (int ntl = 0; ntl < 4; ntl++)
        acc[mt][ntl] = __builtin_amdgcn_mfma_f32_16x16x32_bf16(a[mt], b[ntl], acc[mt][ntl], 0, 0, 0);
  }

  #pragma unroll
  for (int mt = 0; mt < 4; mt++){
    #pragma unroll
    for (int ntl = 0; ntl < 4; ntl++){
      const int t = wave * 4 + ntl;
      const int colb = t * 16 + l16;
      const float bb = b2f(bias[colb]);
      #pragma unroll
      for (int r = 0; r < 4; r++){
        const int row = row0 + mt * 16 + quad * 4 + r;
        if (row < M) Y[(size_t)row * 256 + colb] = f2b(acc[mt][ntl][r] + bb);
      }
    }
  }
}

template<int KA, int KB>
__launch_bounds__(256)
__global__ void linear_both_kernel(const void* __restrict__ XA, int sA,
                                   const unsigned short* __restrict__ BpA,
                                   const unsigned short* __restrict__ biasA,
                                   unsigned short* __restrict__ YA, int MA, int gA,
                                   const void* __restrict__ XB, int sB,
                                   const unsigned short* __restrict__ BpB,
                                   const unsigned short* __restrict__ biasB,
                                   unsigned short* __restrict__ YB, int MB,
                                   const int* __restrict__ flag, int use_flag)
{
  const bool f32 = use_flag && (*flag != 0);
  if ((int)blockIdx.x < gA) linear_body<KA>(XA, sA, f32, BpA, biasA, YA, MA, blockIdx.x);
  else                      linear_body<KB>(XB, sB, f32, BpB, biasB, YB, MB, blockIdx.x - gA);
}

// ================= CSR build =================
__global__ void count_both_kernel(const int* __restrict__ esrc, const int* __restrict__ edst,
                                  int* __restrict__ degU, int* __restrict__ degI, int E){
  int t = blockIdx.x * 256 + threadIdx.x;
  if (t >= E) return;
  atomicAdd(&degI[edst[t]], 1);
  atomicAdd(&degU[esrc[t]], 1);
}

// block-parallel: per-block scan || degree histogram. NO cross-block sync — the
// dispatch boundary is the sync (the R5 ticket+__threadfence version stalled 53 µs
// on ~1000 device-scope fences).
__global__ void scan_hist_par_kernel(const int* __restrict__ degI, const int* __restrict__ degU,
                                     int* __restrict__ rpI, int* __restrict__ rpU,
                                     int* __restrict__ blkI, int* __restrict__ blkU,
                                     int* __restrict__ histI, int* __restrict__ histU,
                                     int NI, int NU, int BI, int BU, int BI2, int BU2){
  const int tid = threadIdx.x;
  const int b = blockIdx.x;
  const int nscan = BI + BU;
  if (b < nscan){
    __shared__ int s[256];
    const int* deg; int* rowptr; int* blksum; int Nd; int bb;
    if (b < BI){ deg = degI; rowptr = rpI; blksum = blkI; Nd = NI; bb = b; }
    else       { deg = degU; rowptr = rpU; blksum = blkU; Nd = NU; bb = b - BI; }
    const int base = bb * 2048 + tid * 8;
    int v[8]; int tot = 0;
    #pragma unroll
    for (int j = 0; j < 8; j++){
      int idx = base + j;
      v[j] = (idx < Nd) ? deg[idx] : 0;
      tot += v[j];
    }
    s[tid] = tot;
    __syncthreads();
    for (int off = 1; off < 256; off <<= 1){
      int add = (tid >= off) ? s[tid - off] : 0;
      __syncthreads();
      s[tid] += add;
      __syncthreads();
    }
    int run = s[tid] - tot;
    #pragma unroll
    for (int j = 0; j < 8; j++){
      int idx = base + j;
      if (idx < Nd) rowptr[idx] = run;
      run += v[j];
    }
    if (tid == 255) blksum[bb] = s[255];
  } else {
    __shared__ int h2[64];
    if (tid < 64) h2[tid] = 0;
    __syncthreads();
    const int bb = b - nscan;
    const int* deg; int* gh; int base; int N;
    if (bb < BI2){ deg = degI; gh = histI; base = bb * 256; N = NI; }
    else         { deg = degU; gh = histU; base = (bb - BI2) * 256; N = NU; }
    const int n = base + tid;
    if (n < N) atomicAdd(&h2[min(deg[n], 63)], 1);
    __syncthreads();
    if (tid < 64 && h2[tid]) atomicAdd(&gh[tid], h2[tid]);
  }
}

// single block: waves 0-1 do blk top-level exclusive scan; waves 2-3 do hist suffix scan
__global__ void tops_kernel(int* __restrict__ blkI, int BI, int* __restrict__ blkU, int BU,
                            int* __restrict__ histI, int* __restrict__ histU){
  const int tid = threadIdx.x;   // 256
  const int lane = tid & 63;
  if (tid < 128){
    int* blk = (tid < 64) ? blkI : blkU;
    const int B = (tid < 64) ? BI : BU;
    int v = (lane < B) ? blk[lane] : 0;
    const int orig = v;
    #pragma unroll
    for (int off = 1; off < 64; off <<= 1){
      int u = __shfl_up(v, off, 64);
      if (lane >= off) v += u;
    }
    if (lane < B) blk[lane] = v - orig;
  } else {
    int* h = (tid < 192) ? histI : histU;
    int v = h[lane];
    int x = v;
    #pragma unroll
    for (int off = 1; off < 64; off <<= 1){
      int u = __shfl_down(x, off, 64);
      x += (lane + off < 64) ? u : 0;
    }
    h[lane] = x - v;
  }
}

__global__ void scan_add2_kernel(int* __restrict__ rpI, int* __restrict__ rpU,
                                 const int* __restrict__ blkI, const int* __restrict__ blkU,
                                 int* __restrict__ curI, int* __restrict__ curU,
                                 int NI, int NU, int BI, int E){
  const int b = blockIdx.x;
  int* rowptr; const int* blksum; int* curs; int Nd; int bb;
  if (b < BI){ rowptr = rpI; blksum = blkI; curs = curI; Nd = NI; bb = b; }
  else       { rowptr = rpU; blksum = blkU; curs = curU; Nd = NU; bb = b - BI; }
  const int base = bb * 2048 + threadIdx.x * 8;
  const int add = blksum[bb];
  #pragma unroll
  for (int j = 0; j < 8; j++){
    int idx = base + j;
    if (idx < Nd){ int v = rowptr[idx] + add; rowptr[idx] = v; curs[idx] = v; }
    else if (idx == Nd) rowptr[idx] = E;
  }
}

// merged: perm scatter (counting-sort placement) + edge scatter, one dispatch
__global__ void scatter_all_kernel(const int* __restrict__ esrc, const int* __restrict__ edst,
                                   int* __restrict__ curI, int* __restrict__ curU,
                                   int* __restrict__ srcI, int* __restrict__ srcU,
                                   const int* __restrict__ rpI, const int* __restrict__ rpU,
                                   int* __restrict__ histI, int* __restrict__ histU,
                                   int* __restrict__ permI, int* __restrict__ permU,
                                   int NI, int NU, int E, int BI2, int BU2){
  const int tid = threadIdx.x;
  const int b = blockIdx.x;
  const int BP = BI2 + BU2;
  if (b < BP){
    __shared__ int h[64];
    __shared__ int cur[64];
    if (tid < 64) h[tid] = 0;
    __syncthreads();
    const int* rp; int* gh; int* perm; int base; int N;
    if (b < BI2){ rp = rpI; gh = histI; perm = permI; base = b * 256; N = NI; }
    else        { rp = rpU; gh = histU; perm = permU; base = (b - BI2) * 256; N = NU; }
    const int n = base + tid;
    int bk = -1;
    if (n < N){ int d = rp[n + 1] - rp[n]; bk = min(d, 63); atomicAdd(&h[bk], 1); }
    __syncthreads();
    if (tid < 64) cur[tid] = h[tid] ? atomicAdd(&gh[tid], h[tid]) : 0;
    __syncthreads();
    if (n < N){ int r = atomicAdd(&cur[bk], 1); perm[r] = n; }
  } else {
    int t = (b - BP) * 256 + tid;
    if (t < E){
      int d = edst[t];
      int pos = atomicAdd(&curI[d], 1);
      srcI[pos] = esrc[t];
    } else if (t < 2 * E){
      int tt = t - E;
      int d = esrc[tt];
      int pos = atomicAdd(&curU[d], 1);
      srcU[pos] = edst[tt];
    }
  }
}

// ================= fused GATv2: 4 nodes/wave (16 lanes each), degree-sorted =================
// R1-exact structure: single online-softmax state, 1 edge/iter, depth-1.5 prefetch, VGPR ~24.
struct GatRel {
  const unsigned short* zlrS; // source features [Ns][256] bf16 (xl at +0)
  const unsigned short* zlrD; // dest features   [Nd][256] bf16 (xr at +128)
  const int* rowptr;
  const int* srcArr;
  const int* perm;            // degree-sorted node ids (descending)
  const unsigned short* att;  // [128]
  const unsigned short* bias; // [128]
  void* out;
  unsigned long long elem_off;
  int Nd;
  int nw;                     // ceil(Nd/4)
};

__launch_bounds__(256)
__global__ void fused_gat_sorted_kernel(GatRel A, GatRel B, int do_relu,
                                        const int* __restrict__ flag, int final_store)
{
  const int wave = threadIdx.x >> 6;
  const int lane = threadIdx.x & 63;
  const int ql = lane & 15;
  const int quad = lane >> 4;
  int gw = blockIdx.x * 4 + wave;
  GatRel R;
  if (gw < A.nw) R = A;
  else {
    gw -= A.nw;
    if (gw >= B.nw) return;
    R = B;
  }

  const int rank = gw * 4 + quad;
  const bool vnode = rank < R.Nd;
  int d = 0;
  if (vnode) d = R.perm[rank];
  int beg = 0, end = 0;
  if (vnode){ beg = R.rowptr[d]; end = R.rowptr[d + 1]; }
  int md = end - beg;
  md = max(md, __shfl_xor(md, 16, 64));
  md = max(md, __shfl_xor(md, 32, 64));

  const uint4* zlS4 = (const uint4*)R.zlrS;
  // xr row of dest node: dims [8*ql, 8*ql+8)
  uint4 rv = ((const uint4*)R.zlrD)[(size_t)d * 32 + 16 + ql];
  float r[8], a[8];
  {
    const unsigned int* rp = (const unsigned int*)&rv;
    #pragma unroll
    for (int j = 0; j < 4; j++){
      r[2*j]   = __uint_as_float(rp[j] << 16);
      r[2*j+1] = __uint_as_float(rp[j] & 0xffff0000u);
    }
  }
  uint4 av = ((const uint4*)R.att)[ql];
  {
    const unsigned int* ap = (const unsigned int*)&av;
    #pragma unroll
    for (int j = 0; j < 4; j++){
      a[2*j]   = __uint_as_float(ap[j] << 16) * LOGSCALE;
      a[2*j+1] = __uint_as_float(ap[j] & 0xffff0000u) * LOGSCALE;
    }
  }

  float m = -1e30f, s = 0.f;
  float acc[8];
  #pragma unroll
  for (int j = 0; j < 8; j++) acc[j] = 0.f;

  if (md > 0){
    const int* sA = R.srcArr;
    int i1 = 0, i2 = 0;
    if (beg < end)     i1 = sA[beg];
    if (beg + 1 < end) i2 = sA[beg + 1];
    uint4 g0 = zlS4[(size_t)i1 * 32 + ql];

    for (int it = 0; it < md; it++){
      uint4 g1 = zlS4[(size_t)i2 * 32 + ql];     // prefetch row for it+1
      int i3 = 0;
      { int ee = beg + it + 2; if (ee < end) i3 = sA[ee]; }   // prefetch idx for it+2
      const bool valid = (beg + it) < end;

      float x[8];
      const unsigned int* gp = (const unsigned int*)&g0;
      #pragma unroll
      for (int j = 0; j < 4; j++){
        x[2*j]   = __uint_as_float(gp[j] << 16);
        x[2*j+1] = __uint_as_float(gp[j] & 0xffff0000u);
      }
      float p = 0.f;
      #pragma unroll
      for (int j = 0; j < 8; j++){
        float t = x[j] + r[j];
        t = fmaxf(t, 0.2f * t);
        p = fmaf(a[j], t, p);
      }
      p = dpp_red8(p);
      const float pv = valid ? p : -1e30f;

      if (__builtin_expect(__any(pv > m + 8.f), 0)){
        const float mn = fmaxf(m, pv);
        const float scO = EXPX(m - mn);
        const float qv = valid ? EXPX(pv - mn) : 0.f;
        s = fmaf(s, scO, qv);
        #pragma unroll
        for (int j = 0; j < 8; j++) acc[j] = fmaf(acc[j], scO, x[j] * qv);
        m = mn;
      } else {
        const float qv = valid ? EXPX(pv - m) : 0.f;
        s += qv;
        #pragma unroll
        for (int j = 0; j < 8; j++) acc[j] = fmaf(x[j], qv, acc[j]);
      }
      g0 = g1; i2 = i3;
    }
  }

  const float inv = 1.f / (s + 1e-16f);
  uint4 bv = ((const uint4*)R.bias)[ql];
  float o[8];
  {
    const unsigned int* bp = (const unsigned int*)&bv;
    #pragma unroll
    for (int j = 0; j < 4; j++){
      o[2*j]   = fmaf(acc[2*j],   inv, __uint_as_float(bp[j] << 16));
      o[2*j+1] = fmaf(acc[2*j+1], inv, __uint_as_float(bp[j] & 0xffff0000u));
    }
  }
  if (do_relu){
    #pragma unroll
    for (int j = 0; j < 8; j++) o[j] = fmaxf(o[j], 0.f);
  }
  if (!vnode) return;
  const size_t eidx = (size_t)R.elem_off + (size_t)d * HDIM + 8 * ql;
  if (final_store && (*flag != 0)){
    float4 f0 = {o[0], o[1], o[2], o[3]};
    float4 f1 = {o[4], o[5], o[6], o[7]};
    float4* op = (float4*)R.out;
    op[eidx >> 2] = f0;
    op[(eidx >> 2) + 1] = f1;
  } else {
    uint4 w;
    unsigned int* wp = (unsigned int*)&w;
    #pragma unroll
    for (int j = 0; j < 4; j++)
      wp[j] = (unsigned int)f2b(o[2*j]) | ((unsigned int)f2b(o[2*j+1]) << 16);
    ((uint4*)R.out)[eidx >> 3] = w;
  }
}

extern "C" void kernel_launch(void* const* d_in, const int* in_sizes, int n_in,
                              void* d_out, int out_size, void* d_ws, size_t ws_size,
                              hipStream_t stream)
{
  const int* esrc = (const int*)d_in[12];
  const int* edst = (const int*)d_in[13];

  const int NU = in_sizes[0] / 64;    // 100000
  const int NI = in_sizes[1] / 128;   // 20000
  const int E  = in_sizes[12];        // 250000
  const size_t fu = (size_t)NU * HDIM, fi = (size_t)NI * HDIM;

  // ---- workspace carve, 256B-aligned regions
  char* w = (char*)d_ws;
  auto carve = [&](size_t bytes){ char* p = w; w += (bytes + 255) & ~(size_t)255; return p; };
  int* flag = (int*)carve(4);
  unsigned short* Wc = (unsigned short*)carve(49664 * 2);
  unsigned short* P  = (unsigned short*)carve((size_t)P_TOT * 2);
  unsigned short* Bp = (unsigned short*)carve(114688 * 2);
  unsigned short* Bc = (unsigned short*)carve(1024 * 2);
  int* rowptrI = (int*)carve(((size_t)NI + 1) * 4);
  int* rowptrU = (int*)carve(((size_t)NU + 1) * 4);
  int* curs    = (int*)carve(((size_t)NI + NU) * 4);
  int* cursI = curs;
  int* cursU = curs + NI;
  int* blkI = (int*)carve(64 * 4);
  int* blkU = (int*)carve(64 * 4);
  int* hists = (int*)carve(128 * 4);       // histI[64] | histU[64]
  int* histI = hists;
  int* histU = hists + 64;
  int* permI = (int*)carve((size_t)NI * 4);
  int* permU = (int*)carve((size_t)NU * 4);
  int* srcI  = (int*)carve((size_t)E * 4);
  int* srcU  = (int*)carve((size_t)E * 4);
  unsigned short* zlrU = (unsigned short*)carve((size_t)NU * 256 * 2);  // [NU][xl|xr]
  unsigned short* zlrI = (unsigned short*)carve((size_t)NI * 256 * 2);  // [NI][xl|xr]
  (void)ws_size; (void)n_in; (void)out_size; (void)fi;

  unsigned short* stage_zu = (unsigned short*)d_out;          // layer-0 bf16 staging
  unsigned short* stage_zi = (unsigned short*)d_out + fu;
  (void)stage_zi;

  // ---- 1: cvt (+sniff +zero curs/hists +publish flag)
  CvtArgs ca;
  const int srcIdx[10] = {2, 4, 6, 8, 7, 9, 10, 11, 3, 5};
  const int lens[10] = {8192, 16384, 65536, 65536, 512, 512, 512, 512, 128, 128};
  for (int i = 0; i < 10; i++){ ca.src[i] = d_in[srcIdx[i]]; ca.len[i] = lens[i]; }
  ca.xsniff = (const unsigned short*)d_in[0];
  cvt_all_kernel<<<(P_TOT + 255) / 256, 256, 0, stream>>>(ca, P, flag,
                                                          curs, NI + NU, hists, 128);
  // ---- 2: prep
  prep_weights_kernel<<<(49664 + 255) / 256, 256, 0, stream>>>(P, Wc);

  const unsigned short* cWlU0 = Wc;                 // [64,128]
  const unsigned short* cWrU1 = Wc + 8192;          // [64,128]
  const unsigned short* cWlI1 = Wc + 16384;         // [128,128]
  const unsigned short* cWrI0 = Wc + 32768;         // [128,128]

  // ---- 3: permute + bias concat (merged)
  PermBiasArgs pa;
  pa.W0[0] = cWlU0;                 pa.W1[0] = cWrU1;                 pa.KS[0] = 2; pa.base[0] = 0;     pa.n[0] = 16384;
  pa.W0[1] = cWlI1;                 pa.W1[1] = cWrI0;                 pa.KS[1] = 4; pa.base[1] = 16384; pa.n[1] = 32768;
  pa.W0[2] = P + P_WL + 2 * 16384;  pa.W1[2] = P + P_WR + 3 * 16384;  pa.KS[2] = 4; pa.base[2] = 49152; pa.n[2] = 32768;
  pa.W0[3] = P + P_WL + 3 * 16384;  pa.W1[3] = P + P_WR + 2 * 16384;  pa.KS[3] = 4; pa.base[3] = 81920; pa.n[3] = 32768;
  pa.blo[0] = Wc + 49152;         pa.bhi[0] = Wc + 49152 + 128;
  pa.blo[1] = Wc + 49152 + 256;   pa.bhi[1] = Wc + 49152 + 384;
  pa.blo[2] = P + P_BL + 256;     pa.bhi[2] = P + P_BR + 384;
  pa.blo[3] = P + P_BL + 384;     pa.bhi[3] = P + P_BR + 256;
  permute_bias_kernel<<<(114688 + 1024 + 255) / 256, 256, 0, stream>>>(pa, Bp, Bc);
  unsigned short* BpU0 = Bp;
  unsigned short* BpI0 = Bp + 16384;
  unsigned short* BpU1 = Bp + 49152;
  unsigned short* BpI1 = Bp + 81920;

  // ---- 4-8: CSR build + degree sort (5 dispatches, no device fences)
  const int BI = (NI + 2047) / 2048, BU = (NU + 2047) / 2048;
  const int BI2 = (NI + 255) / 256, BU2 = (NU + 255) / 256;
  count_both_kernel<<<(E + 255) / 256, 256, 0, stream>>>(esrc, edst, cursU, cursI, E);
  scan_hist_par_kernel<<<BI + BU + BI2 + BU2, 256, 0, stream>>>(
      cursI, cursU, rowptrI, rowptrU, blkI, blkU, histI, histU,
      NI, NU, BI, BU, BI2, BU2);
  tops_kernel<<<1, 256, 0, stream>>>(blkI, BI, blkU, BU, histI, histU);
  scan_add2_kernel<<<BI + BU, 256, 0, stream>>>(rowptrI, rowptrU, blkI, blkU, cursI, cursU, NI, NU, BI, E);
  scatter_all_kernel<<<BI2 + BU2 + (2 * E + 255) / 256, 256, 0, stream>>>(
      esrc, edst, cursI, cursU, srcI, srcU, rowptrI, rowptrU,
      histI, histU, permI, permU, NI, NU, E, BI2, BU2);

  const int gMU = (NU + 63) / 64, gMI = (NI + 63) / 64;
  const int nwA = (NI + 3) / 4, nwB = (NU + 3) / 4;
  const int gGat = (nwA + nwB + 3) / 4;   // 256-thread blocks = 4 waves

  for (int l = 0; l < 2; l++){
    if (l == 0){
      linear_both_kernel<64, 128><<<gMU + gMI, 256, 0, stream>>>(
          d_in[0], 64, BpU0, Bc, zlrU, NU, gMU,
          d_in[1], 128, BpI0, Bc + 256, zlrI, NI, flag, 1);
    } else {
      linear_both_kernel<128, 128><<<gMU + gMI, 256, 0, stream>>>(
          stage_zu, 128, BpU1, Bc + 512, zlrU, NU, gMU,
          stage_zi, 128, BpI1, Bc + 768, zlrI, NI, flag, 0);
    }
    const int relu = (l == 0);
    const int final_store = (l == 1);

    GatRel A, B;
    // rel 0: user -> item (dst=item)
    A.zlrS = zlrU; A.zlrD = zlrI; A.rowptr = rowptrI; A.srcArr = srcI; A.perm = permI;
    A.att  = P + P_ATT + (l * 2 + 0) * HDIM;
    A.bias = P + P_BIA + (l * 2 + 0) * HDIM;
    A.out = final_store ? d_out : (void*)stage_zu; A.elem_off = fu; A.Nd = NI; A.nw = nwA;
    // rel 1: item -> user (dst=user)
    B.zlrS = zlrI; B.zlrD = zlrU; B.rowptr = rowptrU; B.srcArr = srcU; B.perm = permU;
    B.att  = P + P_ATT + (l * 2 + 1) * HDIM;
    B.bias = P + P_BIA + (l * 2 + 1) * HDIM;
    B.out = final_store ? d_out : (void*)stage_zu; B.elem_off = 0; B.Nd = NU; B.nw = nwB;

    fused_gat_sorted_kernel<<<gGat, 256, 0, stream>>>(A, B, relu, flag, final_store);
  }
}

// Round 7
// 317.098 us; speedup vs baseline: 1.1648x; 1.0276x over previous
//
#include <hip/hip_runtime.h>

#define HDIM 128   // hidden = HEADS*D = 2*64

typedef __attribute__((ext_vector_type(8))) short short8;
typedef __attribute__((ext_vector_type(4))) float float4v;

__device__ __forceinline__ float b2f(unsigned short u){
  return __uint_as_float(((unsigned int)u) << 16);
}
__device__ __forceinline__ unsigned short f2b(float f){
  unsigned int x = __float_as_uint(f);
  x += 0x7fffu + ((x >> 16) & 1u);           // round-to-nearest-even
  return (unsigned short)(x >> 16);
}

#if __has_builtin(__builtin_amdgcn_exp2f)
#define EXPX(x) __builtin_amdgcn_exp2f(x)
#define LOGSCALE 1.4426950408889634f
#else
#define EXPX(x) __expf(x)
#define LOGSCALE 1.f
#endif

// sum over each 8-lane group (dims of one head) — pure-VALU DPP tree, no LDS pipe
__device__ __forceinline__ float dpp_red8(float x){
  x += __int_as_float(__builtin_amdgcn_update_dpp(0, __float_as_int(x), 0xB1, 0xF, 0xF, true));  // quad_perm xor1
  x += __int_as_float(__builtin_amdgcn_update_dpp(0, __float_as_int(x), 0x4E, 0xF, 0xF, true));  // quad_perm xor2
  x += __int_as_float(__builtin_amdgcn_update_dpp(0, __float_as_int(x), 0x141, 0xF, 0xF, true)); // row_half_mirror
  return x;
}

// per-block redundant dtype sniff (reads 4 KB of x; L2-hot after first block)
__device__ __forceinline__ int sniff_block(const unsigned short* __restrict__ x){
  const int tid = threadIdx.x;               // 256 threads
  int cnt = 0, tot = 0;
  for (int i = tid * 2; i < 4096; i += 512){
    float v = fabsf(b2f(x[i]));
    tot++;
    if (v > 1e-4f && v < 50.f) cnt++;
  }
  __shared__ int s_cnt[256], s_tot[256];
  s_cnt[tid] = cnt; s_tot[tid] = tot;
  __syncthreads();
  for (int o = 128; o > 0; o >>= 1){
    if (tid < o){ s_cnt[tid] += s_cnt[tid + o]; s_tot[tid] += s_tot[tid + o]; }
    __syncthreads();
  }
  __shared__ int res;
  if (tid == 0) res = (s_cnt[0] * 2 < s_tot[0]) ? 1 : 0;
  __syncthreads();
  return res;
}

// canonical params layout (ushort offsets into P)
#define P_WPU 0
#define P_WPI 8192
#define P_WL  24576
#define P_WR  90112
#define P_BL  155648
#define P_BR  156160
#define P_ATT 156672
#define P_BIA 157184
#define P_BPU 157696
#define P_BPI 157824
#define P_TOT 157952

struct CvtArgs { const void* src[10]; int len[10]; const unsigned short* xsniff; };

// cvt + inline sniff + zero scratch (curs, hists) + publish flag
__global__ void cvt_all_kernel(CvtArgs args, unsigned short* __restrict__ P,
                               int* __restrict__ flag,
                               int* __restrict__ zero1, int nz1,
                               int* __restrict__ zero2, int nz2){
  const int f32 = sniff_block(args.xsniff);
  int t = blockIdx.x * 256 + threadIdx.x;
  if (t < nz1) zero1[t] = 0;
  if (t < nz2) zero2[t] = 0;
  if (t == 0) flag[0] = f32;
  if (t >= P_TOT) return;
  int local = t;
  int i = 0;
  while (local >= args.len[i]){ local -= args.len[i]; i++; }
  if (f32) P[t] = f2b(((const float*)args.src[i])[local]);
  else     P[t] = ((const unsigned short*)args.src[i])[local];
}

// ---------------- prep: compose layer-0 weights  Wc = Wp @ W  (+ bp @ W + b)
__global__ void prep_weights_kernel(const unsigned short* __restrict__ P,
                                    unsigned short* __restrict__ Wc)
{
  const int t = blockIdx.x * 256 + threadIdx.x;
  if (t >= 49664) return;
  const unsigned short* Wl = P + P_WL;
  const unsigned short* Wr = P + P_WR;
  const unsigned short* Bm[4] = { Wl, Wr + 16384, Wl + 16384, Wr };
  const unsigned short* Av[4] = { P + P_WPU, P + P_WPU, P + P_WPI, P + P_WPI };
  const unsigned short* bv[4] = { P + P_BPU, P + P_BPU, P + P_BPI, P + P_BPI };
  const unsigned short* bo[4] = { P + P_BL, P + P_BR + 128, P + P_BL + 128, P + P_BR };
  if (t < 49152){
    int job, base;
    if (t < 8192)       { job = 0; base = 0; }
    else if (t < 16384) { job = 1; base = 8192; }
    else if (t < 32768) { job = 2; base = 16384; }
    else                { job = 3; base = 32768; }
    const int local = t - base;
    const int k = local >> 7, n = local & 127;
    const unsigned short* A = Av[job] + (size_t)k * 128;
    const unsigned short* B = Bm[job];
    float s = 0.f;
    #pragma unroll 4
    for (int h = 0; h < 128; h++) s = fmaf(b2f(A[h]), b2f(B[h * 128 + n]), s);
    Wc[t] = f2b(s);
  } else {
    const int local = t - 49152;
    const int job = local >> 7, n = local & 127;
    const unsigned short* B = Bm[job];
    float s = b2f(bo[job][n]);
    for (int h = 0; h < 128; h++) s = fmaf(b2f(bv[job][h]), b2f(B[h * 128 + n]), s);
    Wc[t] = f2b(s);
  }
}

// ---------------- permute all 4 concat weights into B-fragment order + concat biases (merged)
struct PermBiasArgs { const unsigned short* W0[4]; const unsigned short* W1[4];
                      int KS[4]; int base[4]; int n[4];
                      const unsigned short* blo[4]; const unsigned short* bhi[4]; };
__global__ void permute_bias_kernel(PermBiasArgs pa, unsigned short* __restrict__ dst,
                                    unsigned short* __restrict__ dstB){
  int t = blockIdx.x * 256 + threadIdx.x;
  if (t >= 114688){
    int u = t - 114688;
    if (u < 1024){
      int set = u >> 8, c = u & 255;
      dstB[u] = (c < 128) ? pa.blo[set][c] : pa.bhi[set][c - 128];
    }
    return;
  }
  int job = 0;
  while (job < 4 && t >= pa.base[job] + pa.n[job]) job++;
  if (job >= 4) return;
  int local = t - pa.base[job];
  int KS = pa.KS[job];
  int j = local & 7, rest = local >> 3;
  int l = rest & 63; rest >>= 6;
  int ks = rest % KS, tile = rest / KS;
  int k = ks * 32 + (l >> 4) * 8 + j;
  int c = tile * 16 + (l & 15);
  dst[t] = (c < 128) ? pa.W0[job][k * 128 + c] : pa.W1[job][k * 128 + (c - 128)];
}

// ---------------- MFMA linear body + dual-range kernel (NU and NI jobs in one dispatch)
// Epilogue: stage bf16 tile in LDS, store coalesced uint4 (was: 64 scalar 2B stores/lane).
template<int K>
__device__ __forceinline__ void linear_body(const void* __restrict__ Xv, int xstride,
                                            bool f32,
                                            const unsigned short* __restrict__ Bp,
                                            const unsigned short* __restrict__ bias,
                                            unsigned short* __restrict__ Y, int M, int bx,
                                            unsigned short* __restrict__ lds)
{
  constexpr int KS = K / 32;
  const int wave = threadIdx.x >> 6, lane = threadIdx.x & 63;
  const int quad = lane >> 4, l16 = lane & 15;
  const int row0 = bx * 64;

  float4v acc[4][4];
  const float4v z = {0.f, 0.f, 0.f, 0.f};
  #pragma unroll
  for (int i = 0; i < 4; i++)
    #pragma unroll
    for (int j = 0; j < 4; j++) acc[i][j] = z;

  for (int ks = 0; ks < KS; ks++){
    const int col = ks * 32 + quad * 8;
    short8 a[4];
    #pragma unroll
    for (int mt = 0; mt < 4; mt++){
      int r = row0 + mt * 16 + l16; if (r >= M) r = M - 1;
      if (f32){
        const float* p = (const float*)Xv + (size_t)r * xstride + col;
        float4 v0 = *(const float4*)p;
        float4 v1 = *(const float4*)(p + 4);
        short8 tmp;
        tmp[0] = (short)f2b(v0.x); tmp[1] = (short)f2b(v0.y);
        tmp[2] = (short)f2b(v0.z); tmp[3] = (short)f2b(v0.w);
        tmp[4] = (short)f2b(v1.x); tmp[5] = (short)f2b(v1.y);
        tmp[6] = (short)f2b(v1.z); tmp[7] = (short)f2b(v1.w);
        a[mt] = tmp;
      } else {
        a[mt] = *(const short8*)((const unsigned short*)Xv + (size_t)r * xstride + col);
      }
    }
    short8 b[4];
    #pragma unroll
    for (int ntl = 0; ntl < 4; ntl++){
      const int t = wave * 4 + ntl;
      b[ntl] = *(const short8*)(Bp + ((size_t)(t * KS + ks) * 64 + lane) * 8);
    }
    #pragma unroll
    for (int mt = 0; mt < 4; mt++)
      #pragma unroll
      for (int ntl = 0; ntl < 4; ntl++)
        acc[mt][ntl] = __builtin_amdgcn_mfma_f32_16x16x32_bf16(a[mt], b[ntl], acc[mt][ntl], 0, 0, 0);
  }

  // stage to LDS [64][256] bf16
  #pragma unroll
  for (int mt = 0; mt < 4; mt++){
    #pragma unroll
    for (int ntl = 0; ntl < 4; ntl++){
      const int t = wave * 4 + ntl;
      const int colb = t * 16 + l16;
      const float bb = b2f(bias[colb]);
      #pragma unroll
      for (int r = 0; r < 4; r++){
        const int rl = mt * 16 + quad * 4 + r;
        lds[rl * 256 + colb] = f2b(acc[mt][ntl][r] + bb);
      }
    }
  }
  __syncthreads();
  // coalesced store: 2048 uint4 total, 8 per thread
  const uint4* l4 = (const uint4*)lds;
  #pragma unroll
  for (int i = 0; i < 8; i++){
    const int idx = i * 256 + (int)threadIdx.x;
    const int row = idx >> 5;                  // 32 uint4 per row
    const int grow = row0 + row;
    if (grow < M)
      *((uint4*)(Y + (size_t)grow * 256) + (idx & 31)) = l4[idx];
  }
}

template<int KA, int KB>
__launch_bounds__(256)
__global__ void linear_both_kernel(const void* __restrict__ XA, int sA,
                                   const unsigned short* __restrict__ BpA,
                                   const unsigned short* __restrict__ biasA,
                                   unsigned short* __restrict__ YA, int MA, int gA,
                                   const void* __restrict__ XB, int sB,
                                   const unsigned short* __restrict__ BpB,
                                   const unsigned short* __restrict__ biasB,
                                   unsigned short* __restrict__ YB, int MB,
                                   const int* __restrict__ flag, int use_flag)
{
  __shared__ unsigned short lds[64 * 256];     // 32 KB
  const bool f32 = use_flag && (*flag != 0);
  if ((int)blockIdx.x < gA) linear_body<KA>(XA, sA, f32, BpA, biasA, YA, MA, blockIdx.x, lds);
  else                      linear_body<KB>(XB, sB, f32, BpB, biasB, YB, MB, blockIdx.x - gA, lds);
}

// ================= CSR build =================
__global__ void count_both_kernel(const int* __restrict__ esrc, const int* __restrict__ edst,
                                  int* __restrict__ degU, int* __restrict__ degI, int E){
  int t = blockIdx.x * 256 + threadIdx.x;
  if (t >= E) return;
  atomicAdd(&degI[edst[t]], 1);
  atomicAdd(&degU[esrc[t]], 1);
}

// block-parallel: per-block scan || degree histogram. NO cross-block sync — the
// dispatch boundary is the sync.
__global__ void scan_hist_par_kernel(const int* __restrict__ degI, const int* __restrict__ degU,
                                     int* __restrict__ rpI, int* __restrict__ rpU,
                                     int* __restrict__ blkI, int* __restrict__ blkU,
                                     int* __restrict__ histI, int* __restrict__ histU,
                                     int NI, int NU, int BI, int BU, int BI2, int BU2){
  const int tid = threadIdx.x;
  const int b = blockIdx.x;
  const int nscan = BI + BU;
  if (b < nscan){
    __shared__ int s[256];
    const int* deg; int* rowptr; int* blksum; int Nd; int bb;
    if (b < BI){ deg = degI; rowptr = rpI; blksum = blkI; Nd = NI; bb = b; }
    else       { deg = degU; rowptr = rpU; blksum = blkU; Nd = NU; bb = b - BI; }
    const int base = bb * 2048 + tid * 8;
    int v[8]; int tot = 0;
    #pragma unroll
    for (int j = 0; j < 8; j++){
      int idx = base + j;
      v[j] = (idx < Nd) ? deg[idx] : 0;
      tot += v[j];
    }
    s[tid] = tot;
    __syncthreads();
    for (int off = 1; off < 256; off <<= 1){
      int add = (tid >= off) ? s[tid - off] : 0;
      __syncthreads();
      s[tid] += add;
      __syncthreads();
    }
    int run = s[tid] - tot;
    #pragma unroll
    for (int j = 0; j < 8; j++){
      int idx = base + j;
      if (idx < Nd) rowptr[idx] = run;
      run += v[j];
    }
    if (tid == 255) blksum[bb] = s[255];
  } else {
    __shared__ int h2[64];
    if (tid < 64) h2[tid] = 0;
    __syncthreads();
    const int bb = b - nscan;
    const int* deg; int* gh; int base; int N;
    if (bb < BI2){ deg = degI; gh = histI; base = bb * 256; N = NI; }
    else         { deg = degU; gh = histU; base = (bb - BI2) * 256; N = NU; }
    const int n = base + tid;
    if (n < N) atomicAdd(&h2[min(deg[n], 63)], 1);
    __syncthreads();
    if (tid < 64 && h2[tid]) atomicAdd(&gh[tid], h2[tid]);
  }
}

// single block: waves 0-1 do blk top-level exclusive scan; waves 2-3 do hist suffix scan
__global__ void tops_kernel(int* __restrict__ blkI, int BI, int* __restrict__ blkU, int BU,
                            int* __restrict__ histI, int* __restrict__ histU){
  const int tid = threadIdx.x;   // 256
  const int lane = tid & 63;
  if (tid < 128){
    int* blk = (tid < 64) ? blkI : blkU;
    const int B = (tid < 64) ? BI : BU;
    int v = (lane < B) ? blk[lane] : 0;
    const int orig = v;
    #pragma unroll
    for (int off = 1; off < 64; off <<= 1){
      int u = __shfl_up(v, off, 64);
      if (lane >= off) v += u;
    }
    if (lane < B) blk[lane] = v - orig;
  } else {
    int* h = (tid < 192) ? histI : histU;
    int v = h[lane];
    int x = v;
    #pragma unroll
    for (int off = 1; off < 64; off <<= 1){
      int u = __shfl_down(x, off, 64);
      x += (lane + off < 64) ? u : 0;
    }
    h[lane] = x - v;
  }
}

__global__ void scan_add2_kernel(int* __restrict__ rpI, int* __restrict__ rpU,
                                 const int* __restrict__ blkI, const int* __restrict__ blkU,
                                 int* __restrict__ curI, int* __restrict__ curU,
                                 int NI, int NU, int BI, int E){
  const int b = blockIdx.x;
  int* rowptr; const int* blksum; int* curs; int Nd; int bb;
  if (b < BI){ rowptr = rpI; blksum = blkI; curs = curI; Nd = NI; bb = b; }
  else       { rowptr = rpU; blksum = blkU; curs = curU; Nd = NU; bb = b - BI; }
  const int base = bb * 2048 + threadIdx.x * 8;
  const int add = blksum[bb];
  #pragma unroll
  for (int j = 0; j < 8; j++){
    int idx = base + j;
    if (idx < Nd){ int v = rowptr[idx] + add; rowptr[idx] = v; curs[idx] = v; }
    else if (idx == Nd) rowptr[idx] = E;
  }
}

// merged: perm scatter (counting-sort placement) + edge scatter, one dispatch
__global__ void scatter_all_kernel(const int* __restrict__ esrc, const int* __restrict__ edst,
                                   int* __restrict__ curI, int* __restrict__ curU,
                                   int* __restrict__ srcI, int* __restrict__ srcU,
                                   const int* __restrict__ rpI, const int* __restrict__ rpU,
                                   int* __restrict__ histI, int* __restrict__ histU,
                                   int* __restrict__ permI, int* __restrict__ permU,
                                   int NI, int NU, int E, int BI2, int BU2){
  const int tid = threadIdx.x;
  const int b = blockIdx.x;
  const int BP = BI2 + BU2;
  if (b < BP){
    __shared__ int h[64];
    __shared__ int cur[64];
    if (tid < 64) h[tid] = 0;
    __syncthreads();
    const int* rp; int* gh; int* perm; int base; int N;
    if (b < BI2){ rp = rpI; gh = histI; perm = permI; base = b * 256; N = NI; }
    else        { rp = rpU; gh = histU; perm = permU; base = (b - BI2) * 256; N = NU; }
    const int n = base + tid;
    int bk = -1;
    if (n < N){ int d = rp[n + 1] - rp[n]; bk = min(d, 63); atomicAdd(&h[bk], 1); }
    __syncthreads();
    if (tid < 64) cur[tid] = h[tid] ? atomicAdd(&gh[tid], h[tid]) : 0;
    __syncthreads();
    if (n < N){ int r = atomicAdd(&cur[bk], 1); perm[r] = n; }
  } else {
    int t = (b - BP) * 256 + tid;
    if (t < E){
      int d = edst[t];
      int pos = atomicAdd(&curI[d], 1);
      srcI[pos] = esrc[t];
    } else if (t < 2 * E){
      int tt = t - E;
      int d = esrc[tt];
      int pos = atomicAdd(&curU[d], 1);
      srcU[pos] = edst[tt];
    }
  }
}

// ================= fused GATv2: 4 nodes/wave (16 lanes each), degree-sorted =================
// R1-exact structure: single online-softmax state, 1 edge/iter, depth-1.5 prefetch, VGPR ~24.
struct GatRel {
  const unsigned short* zlrS; // source features [Ns][256] bf16 (xl at +0)
  const unsigned short* zlrD; // dest features   [Nd][256] bf16 (xr at +128)
  const int* rowptr;
  const int* srcArr;
  const int* perm;            // degree-sorted node ids (descending)
  const unsigned short* att;  // [128]
  const unsigned short* bias; // [128]
  void* out;
  unsigned long long elem_off;
  int Nd;
  int nw;                     // ceil(Nd/4)
};

__launch_bounds__(256)
__global__ void fused_gat_sorted_kernel(GatRel A, GatRel B, int do_relu,
                                        const int* __restrict__ flag, int final_store)
{
  const int wave = threadIdx.x >> 6;
  const int lane = threadIdx.x & 63;
  const int ql = lane & 15;
  const int quad = lane >> 4;
  int gw = blockIdx.x * 4 + wave;
  GatRel R;
  if (gw < A.nw) R = A;
  else {
    gw -= A.nw;
    if (gw >= B.nw) return;
    R = B;
  }

  const int rank = gw * 4 + quad;
  const bool vnode = rank < R.Nd;
  int d = 0;
  if (vnode) d = R.perm[rank];
  int beg = 0, end = 0;
  if (vnode){ beg = R.rowptr[d]; end = R.rowptr[d + 1]; }
  int md = end - beg;
  md = max(md, __shfl_xor(md, 16, 64));
  md = max(md, __shfl_xor(md, 32, 64));

  const uint4* zlS4 = (const uint4*)R.zlrS;
  // xr row of dest node: dims [8*ql, 8*ql+8)
  uint4 rv = ((const uint4*)R.zlrD)[(size_t)d * 32 + 16 + ql];
  float r[8], a[8];
  {
    const unsigned int* rp = (const unsigned int*)&rv;
    #pragma unroll
    for (int j = 0; j < 4; j++){
      r[2*j]   = __uint_as_float(rp[j] << 16);
      r[2*j+1] = __uint_as_float(rp[j] & 0xffff0000u);
    }
  }
  uint4 av = ((const uint4*)R.att)[ql];
  {
    const unsigned int* ap = (const unsigned int*)&av;
    #pragma unroll
    for (int j = 0; j < 4; j++){
      a[2*j]   = __uint_as_float(ap[j] << 16) * LOGSCALE;
      a[2*j+1] = __uint_as_float(ap[j] & 0xffff0000u) * LOGSCALE;
    }
  }

  float m = -1e30f, s = 0.f;
  float acc[8];
  #pragma unroll
  for (int j = 0; j < 8; j++) acc[j] = 0.f;

  if (md > 0){
    const int* sA = R.srcArr;
    int i1 = 0, i2 = 0;
    if (beg < end)     i1 = sA[beg];
    if (beg + 1 < end) i2 = sA[beg + 1];
    uint4 g0 = zlS4[(size_t)i1 * 32 + ql];

    for (int it = 0; it < md; it++){
      uint4 g1 = zlS4[(size_t)i2 * 32 + ql];     // prefetch row for it+1
      int i3 = 0;
      { int ee = beg + it + 2; if (ee < end) i3 = sA[ee]; }   // prefetch idx for it+2
      const bool valid = (beg + it) < end;

      float x[8];
      const unsigned int* gp = (const unsigned int*)&g0;
      #pragma unroll
      for (int j = 0; j < 4; j++){
        x[2*j]   = __uint_as_float(gp[j] << 16);
        x[2*j+1] = __uint_as_float(gp[j] & 0xffff0000u);
      }
      float p = 0.f;
      #pragma unroll
      for (int j = 0; j < 8; j++){
        float t = x[j] + r[j];
        t = fmaxf(t, 0.2f * t);
        p = fmaf(a[j], t, p);
      }
      p = dpp_red8(p);
      const float pv = valid ? p : -1e30f;

      if (__builtin_expect(__any(pv > m + 8.f), 0)){
        const float mn = fmaxf(m, pv);
        const float scO = EXPX(m - mn);
        const float qv = valid ? EXPX(pv - mn) : 0.f;
        s = fmaf(s, scO, qv);
        #pragma unroll
        for (int j = 0; j < 8; j++) acc[j] = fmaf(acc[j], scO, x[j] * qv);
        m = mn;
      } else {
        const float qv = valid ? EXPX(pv - m) : 0.f;
        s += qv;
        #pragma unroll
        for (int j = 0; j < 8; j++) acc[j] = fmaf(x[j], qv, acc[j]);
      }
      g0 = g1; i2 = i3;
    }
  }

  const float inv = 1.f / (s + 1e-16f);
  uint4 bv = ((const uint4*)R.bias)[ql];
  float o[8];
  {
    const unsigned int* bp = (const unsigned int*)&bv;
    #pragma unroll
    for (int j = 0; j < 4; j++){
      o[2*j]   = fmaf(acc[2*j],   inv, __uint_as_float(bp[j] << 16));
      o[2*j+1] = fmaf(acc[2*j+1], inv, __uint_as_float(bp[j] & 0xffff0000u));
    }
  }
  if (do_relu){
    #pragma unroll
    for (int j = 0; j < 8; j++) o[j] = fmaxf(o[j], 0.f);
  }
  if (!vnode) return;
  const size_t eidx = (size_t)R.elem_off + (size_t)d * HDIM + 8 * ql;
  if (final_store && (*flag != 0)){
    float4 f0 = {o[0], o[1], o[2], o[3]};
    float4 f1 = {o[4], o[5], o[6], o[7]};
    float4* op = (float4*)R.out;
    op[eidx >> 2] = f0;
    op[(eidx >> 2) + 1] = f1;
  } else {
    uint4 w;
    unsigned int* wp = (unsigned int*)&w;
    #pragma unroll
    for (int j = 0; j < 4; j++)
      wp[j] = (unsigned int)f2b(o[2*j]) | ((unsigned int)f2b(o[2*j+1]) << 16);
    ((uint4*)R.out)[eidx >> 3] = w;
  }
}

extern "C" void kernel_launch(void* const* d_in, const int* in_sizes, int n_in,
                              void* d_out, int out_size, void* d_ws, size_t ws_size,
                              hipStream_t stream)
{
  const int* esrc = (const int*)d_in[12];
  const int* edst = (const int*)d_in[13];

  const int NU = in_sizes[0] / 64;    // 100000
  const int NI = in_sizes[1] / 128;   // 20000
  const int E  = in_sizes[12];        // 250000
  const size_t fu = (size_t)NU * HDIM, fi = (size_t)NI * HDIM;

  // ---- workspace carve, 256B-aligned regions
  char* w = (char*)d_ws;
  auto carve = [&](size_t bytes){ char* p = w; w += (bytes + 255) & ~(size_t)255; return p; };
  int* flag = (int*)carve(4);
  unsigned short* Wc = (unsigned short*)carve(49664 * 2);
  unsigned short* P  = (unsigned short*)carve((size_t)P_TOT * 2);
  unsigned short* Bp = (unsigned short*)carve(114688 * 2);
  unsigned short* Bc = (unsigned short*)carve(1024 * 2);
  int* rowptrI = (int*)carve(((size_t)NI + 1) * 4);
  int* rowptrU = (int*)carve(((size_t)NU + 1) * 4);
  int* curs    = (int*)carve(((size_t)NI + NU) * 4);
  int* cursI = curs;
  int* cursU = curs + NI;
  int* blkI = (int*)carve(64 * 4);
  int* blkU = (int*)carve(64 * 4);
  int* hists = (int*)carve(128 * 4);       // histI[64] | histU[64]
  int* histI = hists;
  int* histU = hists + 64;
  int* permI = (int*)carve((size_t)NI * 4);
  int* permU = (int*)carve((size_t)NU * 4);
  int* srcI  = (int*)carve((size_t)E * 4);
  int* srcU  = (int*)carve((size_t)E * 4);
  unsigned short* zlrU = (unsigned short*)carve((size_t)NU * 256 * 2);  // [NU][xl|xr]
  unsigned short* zlrI = (unsigned short*)carve((size_t)NI * 256 * 2);  // [NI][xl|xr]
  (void)ws_size; (void)n_in; (void)out_size; (void)fi;

  unsigned short* stage_zu = (unsigned short*)d_out;          // layer-0 bf16 staging
  unsigned short* stage_zi = (unsigned short*)d_out + fu;
  (void)stage_zi;

  // ---- 1: cvt (+sniff +zero curs/hists +publish flag)
  CvtArgs ca;
  const int srcIdx[10] = {2, 4, 6, 8, 7, 9, 10, 11, 3, 5};
  const int lens[10] = {8192, 16384, 65536, 65536, 512, 512, 512, 512, 128, 128};
  for (int i = 0; i < 10; i++){ ca.src[i] = d_in[srcIdx[i]]; ca.len[i] = lens[i]; }
  ca.xsniff = (const unsigned short*)d_in[0];
  cvt_all_kernel<<<(P_TOT + 255) / 256, 256, 0, stream>>>(ca, P, flag,
                                                          curs, NI + NU, hists, 128);
  // ---- 2: prep
  prep_weights_kernel<<<(49664 + 255) / 256, 256, 0, stream>>>(P, Wc);

  const unsigned short* cWlU0 = Wc;                 // [64,128]
  const unsigned short* cWrU1 = Wc + 8192;          // [64,128]
  const unsigned short* cWlI1 = Wc + 16384;         // [128,128]
  const unsigned short* cWrI0 = Wc + 32768;         // [128,128]

  // ---- 3: permute + bias concat (merged)
  PermBiasArgs pa;
  pa.W0[0] = cWlU0;                 pa.W1[0] = cWrU1;                 pa.KS[0] = 2; pa.base[0] = 0;     pa.n[0] = 16384;
  pa.W0[1] = cWlI1;                 pa.W1[1] = cWrI0;                 pa.KS[1] = 4; pa.base[1] = 16384; pa.n[1] = 32768;
  pa.W0[2] = P + P_WL + 2 * 16384;  pa.W1[2] = P + P_WR + 3 * 16384;  pa.KS[2] = 4; pa.base[2] = 49152; pa.n[2] = 32768;
  pa.W0[3] = P + P_WL + 3 * 16384;  pa.W1[3] = P + P_WR + 2 * 16384;  pa.KS[3] = 4; pa.base[3] = 81920; pa.n[3] = 32768;
  pa.blo[0] = Wc + 49152;         pa.bhi[0] = Wc + 49152 + 128;
  pa.blo[1] = Wc + 49152 + 256;   pa.bhi[1] = Wc + 49152 + 384;
  pa.blo[2] = P + P_BL + 256;     pa.bhi[2] = P + P_BR + 384;
  pa.blo[3] = P + P_BL + 384;     pa.bhi[3] = P + P_BR + 256;
  permute_bias_kernel<<<(114688 + 1024 + 255) / 256, 256, 0, stream>>>(pa, Bp, Bc);
  unsigned short* BpU0 = Bp;
  unsigned short* BpI0 = Bp + 16384;
  unsigned short* BpU1 = Bp + 49152;
  unsigned short* BpI1 = Bp + 81920;

  // ---- 4-8: CSR build + degree sort (5 dispatches, no device fences)
  const int BI = (NI + 2047) / 2048, BU = (NU + 2047) / 2048;
  const int BI2 = (NI + 255) / 256, BU2 = (NU + 255) / 256;
  count_both_kernel<<<(E + 255) / 256, 256, 0, stream>>>(esrc, edst, cursU, cursI, E);
  scan_hist_par_kernel<<<BI + BU + BI2 + BU2, 256, 0, stream>>>(
      cursI, cursU, rowptrI, rowptrU, blkI, blkU, histI, histU,
      NI, NU, BI, BU, BI2, BU2);
  tops_kernel<<<1, 256, 0, stream>>>(blkI, BI, blkU, BU, histI, histU);
  scan_add2_kernel<<<BI + BU, 256, 0, stream>>>(rowptrI, rowptrU, blkI, blkU, cursI, cursU, NI, NU, BI, E);
  scatter_all_kernel<<<BI2 + BU2 + (2 * E + 255) / 256, 256, 0, stream>>>(
      esrc, edst, cursI, cursU, srcI, srcU, rowptrI, rowptrU,
      histI, histU, permI, permU, NI, NU, E, BI2, BU2);

  const int gMU = (NU + 63) / 64, gMI = (NI + 63) / 64;
  const int nwA = (NI + 3) / 4, nwB = (NU + 3) / 4;
  const int gGat = (nwA + nwB + 3) / 4;   // 256-thread blocks = 4 waves

  for (int l = 0; l < 2; l++){
    if (l == 0){
      linear_both_kernel<64, 128><<<gMU + gMI, 256, 0, stream>>>(
          d_in[0], 64, BpU0, Bc, zlrU, NU, gMU,
          d_in[1], 128, BpI0, Bc + 256, zlrI, NI, flag, 1);
    } else {
      linear_both_kernel<128, 128><<<gMU + gMI, 256, 0, stream>>>(
          stage_zu, 128, BpU1, Bc + 512, zlrU, NU, gMU,
          stage_zi, 128, BpI1, Bc + 768, zlrI, NI, flag, 0);
    }
    const int relu = (l == 0);
    const int final_store = (l == 1);

    GatRel A, B;
    // rel 0: user -> item (dst=item)
    A.zlrS = zlrU; A.zlrD = zlrI; A.rowptr = rowptrI; A.srcArr = srcI; A.perm = permI;
    A.att  = P + P_ATT + (l * 2 + 0) * HDIM;
    A.bias = P + P_BIA + (l * 2 + 0) * HDIM;
    A.out = final_store ? d_out : (void*)stage_zu; A.elem_off = fu; A.Nd = NI; A.nw = nwA;
    // rel 1: item -> user (dst=user)
    B.zlrS = zlrI; B.zlrD = zlrU; B.rowptr = rowptrU; B.srcArr = srcU; B.perm = permU;
    B.att  = P + P_ATT + (l * 2 + 1) * HDIM;
    B.bias = P + P_BIA + (l * 2 + 1) * HDIM;
    B.out = final_store ? d_out : (void*)stage_zu; B.elem_off = 0; B.Nd = NU; B.nw = nwB;

    fused_gat_sorted_kernel<<<gGat, 256, 0, stream>>>(A, B, relu, flag, final_store);
  }
}

// Round 8
// 301.195 us; speedup vs baseline: 1.2263x; 1.0528x over previous
//
#include <hip/hip_runtime.h>

#define HDIM 128   // hidden = HEADS*D = 2*64

typedef __attribute__((ext_vector_type(8))) short short8;
typedef __attribute__((ext_vector_type(4))) float float4v;

__device__ __forceinline__ float b2f(unsigned short u){
  return __uint_as_float(((unsigned int)u) << 16);
}
__device__ __forceinline__ unsigned short f2b(float f){
  unsigned int x = __float_as_uint(f);
  x += 0x7fffu + ((x >> 16) & 1u);           // round-to-nearest-even
  return (unsigned short)(x >> 16);
}

#if __has_builtin(__builtin_amdgcn_exp2f)
#define EXPX(x) __builtin_amdgcn_exp2f(x)
#define LOGSCALE 1.4426950408889634f
#else
#define EXPX(x) __expf(x)
#define LOGSCALE 1.f
#endif

// sum over each 8-lane group (dims of one head) — pure-VALU DPP tree, no LDS pipe
__device__ __forceinline__ float dpp_red8(float x){
  x += __int_as_float(__builtin_amdgcn_update_dpp(0, __float_as_int(x), 0xB1, 0xF, 0xF, true));  // quad_perm xor1
  x += __int_as_float(__builtin_amdgcn_update_dpp(0, __float_as_int(x), 0x4E, 0xF, 0xF, true));  // quad_perm xor2
  x += __int_as_float(__builtin_amdgcn_update_dpp(0, __float_as_int(x), 0x141, 0xF, 0xF, true)); // row_half_mirror
  return x;
}

// per-block redundant dtype sniff (reads 4 KB of x; L2-hot after first block)
__device__ __forceinline__ int sniff_block(const unsigned short* __restrict__ x){
  const int tid = threadIdx.x;               // 256 threads
  int cnt = 0, tot = 0;
  for (int i = tid * 2; i < 4096; i += 512){
    float v = fabsf(b2f(x[i]));
    tot++;
    if (v > 1e-4f && v < 50.f) cnt++;
  }
  __shared__ int s_cnt[256], s_tot[256];
  s_cnt[tid] = cnt; s_tot[tid] = tot;
  __syncthreads();
  for (int o = 128; o > 0; o >>= 1){
    if (tid < o){ s_cnt[tid] += s_cnt[tid + o]; s_tot[tid] += s_tot[tid + o]; }
    __syncthreads();
  }
  __shared__ int res;
  if (tid == 0) res = (s_cnt[0] * 2 < s_tot[0]) ? 1 : 0;
  __syncthreads();
  return res;
}

// canonical params layout (ushort offsets into P)
#define P_WPU 0
#define P_WPI 8192
#define P_WL  24576
#define P_WR  90112
#define P_BL  155648
#define P_BR  156160
#define P_ATT 156672
#define P_BIA 157184
#define P_BPU 157696
#define P_BPI 157824
#define P_TOT 157952

struct CvtArgs { const void* src[10]; int len[10]; const unsigned short* xsniff; };

// cvt + inline sniff + zero scratch (curs, hists) + publish flag
__global__ void cvt_all_kernel(CvtArgs args, unsigned short* __restrict__ P,
                               int* __restrict__ flag,
                               int* __restrict__ zero1, int nz1,
                               int* __restrict__ zero2, int nz2){
  const int f32 = sniff_block(args.xsniff);
  int t = blockIdx.x * 256 + threadIdx.x;
  if (t < nz1) zero1[t] = 0;
  if (t < nz2) zero2[t] = 0;
  if (t == 0) flag[0] = f32;
  if (t >= P_TOT) return;
  int local = t;
  int i = 0;
  while (local >= args.len[i]){ local -= args.len[i]; i++; }
  if (f32) P[t] = f2b(((const float*)args.src[i])[local]);
  else     P[t] = ((const unsigned short*)args.src[i])[local];
}

// ---------------- prep: compose layer-0 weights  Wc = Wp @ W  (+ bp @ W + b)
__global__ void prep_weights_kernel(const unsigned short* __restrict__ P,
                                    unsigned short* __restrict__ Wc)
{
  const int t = blockIdx.x * 256 + threadIdx.x;
  if (t >= 49664) return;
  const unsigned short* Wl = P + P_WL;
  const unsigned short* Wr = P + P_WR;
  const unsigned short* Bm[4] = { Wl, Wr + 16384, Wl + 16384, Wr };
  const unsigned short* Av[4] = { P + P_WPU, P + P_WPU, P + P_WPI, P + P_WPI };
  const unsigned short* bv[4] = { P + P_BPU, P + P_BPU, P + P_BPI, P + P_BPI };
  const unsigned short* bo[4] = { P + P_BL, P + P_BR + 128, P + P_BL + 128, P + P_BR };
  if (t < 49152){
    int job, base;
    if (t < 8192)       { job = 0; base = 0; }
    else if (t < 16384) { job = 1; base = 8192; }
    else if (t < 32768) { job = 2; base = 16384; }
    else                { job = 3; base = 32768; }
    const int local = t - base;
    const int k = local >> 7, n = local & 127;
    const unsigned short* A = Av[job] + (size_t)k * 128;
    const unsigned short* B = Bm[job];
    float s = 0.f;
    #pragma unroll 4
    for (int h = 0; h < 128; h++) s = fmaf(b2f(A[h]), b2f(B[h * 128 + n]), s);
    Wc[t] = f2b(s);
  } else {
    const int local = t - 49152;
    const int job = local >> 7, n = local & 127;
    const unsigned short* B = Bm[job];
    float s = b2f(bo[job][n]);
    for (int h = 0; h < 128; h++) s = fmaf(b2f(bv[job][h]), b2f(B[h * 128 + n]), s);
    Wc[t] = f2b(s);
  }
}

// ---------------- permute all 4 concat weights into B-fragment order + concat biases (merged)
struct PermBiasArgs { const unsigned short* W0[4]; const unsigned short* W1[4];
                      int KS[4]; int base[4]; int n[4];
                      const unsigned short* blo[4]; const unsigned short* bhi[4]; };
__global__ void permute_bias_kernel(PermBiasArgs pa, unsigned short* __restrict__ dst,
                                    unsigned short* __restrict__ dstB){
  int t = blockIdx.x * 256 + threadIdx.x;
  if (t >= 114688){
    int u = t - 114688;
    if (u < 1024){
      int set = u >> 8, c = u & 255;
      dstB[u] = (c < 128) ? pa.blo[set][c] : pa.bhi[set][c - 128];
    }
    return;
  }
  int job = 0;
  while (job < 4 && t >= pa.base[job] + pa.n[job]) job++;
  if (job >= 4) return;
  int local = t - pa.base[job];
  int KS = pa.KS[job];
  int j = local & 7, rest = local >> 3;
  int l = rest & 63; rest >>= 6;
  int ks = rest % KS, tile = rest / KS;
  int k = ks * 32 + (l >> 4) * 8 + j;
  int c = tile * 16 + (l & 15);
  dst[t] = (c < 128) ? pa.W0[job][k * 128 + c] : pa.W1[job][k * 128 + (c - 128)];
}

// ---------------- MFMA linear: A-tile staged through LDS (coalesced streaming loads).
// LDS row stride K+8 elems (272 B for K=128) keeps 16B alignment; fragment ds_reads 2-way aliased.
template<int K>
__device__ __forceinline__ void linear_body(const void* __restrict__ Xv, int xstride,
                                            bool f32,
                                            const unsigned short* __restrict__ Bp,
                                            const unsigned short* __restrict__ bias,
                                            unsigned short* __restrict__ Y, int M, int bx,
                                            unsigned short* __restrict__ lds)
{
  constexpr int KS = K / 32;
  constexpr int LK = K + 8;                  // padded LDS row stride (ushorts)
  constexpr int ROUNDS = (64 * K) / 2048;    // 2 for K=64, 4 for K=128
  const int wave = threadIdx.x >> 6, lane = threadIdx.x & 63;
  const int quad = lane >> 4, l16 = lane & 15;
  const int row0 = bx * 64;

  // ---- stage A tile [64][K] -> LDS, coalesced (8 elems / thread / round)
  #pragma unroll
  for (int rd = 0; rd < ROUNDS; rd++){
    const int e = rd * 2048 + (int)threadIdx.x * 8;
    const int rr = e / K, cc = e % K;        // K is power of two
    int grow = row0 + rr; if (grow >= M) grow = M - 1;
    unsigned short* dst = lds + rr * LK + cc;
    if (f32){
      const float* p = (const float*)Xv + (size_t)grow * xstride + cc;
      float4 v0 = *(const float4*)p;
      float4 v1 = *(const float4*)(p + 4);
      short8 tmp;
      tmp[0] = (short)f2b(v0.x); tmp[1] = (short)f2b(v0.y);
      tmp[2] = (short)f2b(v0.z); tmp[3] = (short)f2b(v0.w);
      tmp[4] = (short)f2b(v1.x); tmp[5] = (short)f2b(v1.y);
      tmp[6] = (short)f2b(v1.z); tmp[7] = (short)f2b(v1.w);
      *(short8*)dst = tmp;
    } else {
      *(short8*)dst = *(const short8*)((const unsigned short*)Xv + (size_t)grow * xstride + cc);
    }
  }
  __syncthreads();

  float4v acc[4][4];
  const float4v z = {0.f, 0.f, 0.f, 0.f};
  #pragma unroll
  for (int i = 0; i < 4; i++)
    #pragma unroll
    for (int j = 0; j < 4; j++) acc[i][j] = z;

  #pragma unroll
  for (int ks = 0; ks < KS; ks++){
    const int col = ks * 32 + quad * 8;
    short8 a[4];
    #pragma unroll
    for (int mt = 0; mt < 4; mt++)
      a[mt] = *(const short8*)(lds + (mt * 16 + l16) * LK + col);   // ds_read_b128, 2-way
    short8 b[4];
    #pragma unroll
    for (int ntl = 0; ntl < 4; ntl++){
      const int t = wave * 4 + ntl;
      b[ntl] = *(const short8*)(Bp + ((size_t)(t * KS + ks) * 64 + lane) * 8);
    }
    #pragma unroll
    for (int mt = 0; mt < 4; mt++)
      #pragma unroll
      for (int ntl = 0; ntl < 4; ntl++)
        acc[mt][ntl] = __builtin_amdgcn_mfma_f32_16x16x32_bf16(a[mt], b[ntl], acc[mt][ntl], 0, 0, 0);
  }

  #pragma unroll
  for (int mt = 0; mt < 4; mt++){
    #pragma unroll
    for (int ntl = 0; ntl < 4; ntl++){
      const int t = wave * 4 + ntl;
      const int colb = t * 16 + l16;
      const float bb = b2f(bias[colb]);
      #pragma unroll
      for (int r = 0; r < 4; r++){
        const int row = row0 + mt * 16 + quad * 4 + r;
        if (row < M) Y[(size_t)row * 256 + colb] = f2b(acc[mt][ntl][r] + bb);
      }
    }
  }
}

template<int KA, int KB>
__launch_bounds__(256)
__global__ void linear_both_kernel(const void* __restrict__ XA, int sA,
                                   const unsigned short* __restrict__ BpA,
                                   const unsigned short* __restrict__ biasA,
                                   unsigned short* __restrict__ YA, int MA, int gA,
                                   const void* __restrict__ XB, int sB,
                                   const unsigned short* __restrict__ BpB,
                                   const unsigned short* __restrict__ biasB,
                                   unsigned short* __restrict__ YB, int MB,
                                   const int* __restrict__ flag, int use_flag)
{
  __shared__ unsigned short lds[64 * 136];     // max K=128 padded: 17408 B
  const bool f32 = use_flag && (*flag != 0);
  if ((int)blockIdx.x < gA) linear_body<KA>(XA, sA, f32, BpA, biasA, YA, MA, blockIdx.x, lds);
  else                      linear_body<KB>(XB, sB, f32, BpB, biasB, YB, MB, blockIdx.x - gA, lds);
}

// ================= CSR build =================
__global__ void count_both_kernel(const int* __restrict__ esrc, const int* __restrict__ edst,
                                  int* __restrict__ degU, int* __restrict__ degI, int E){
  int t = blockIdx.x * 256 + threadIdx.x;
  if (t >= E) return;
  atomicAdd(&degI[edst[t]], 1);
  atomicAdd(&degU[esrc[t]], 1);
}

// block-parallel: per-block scan || degree histogram. NO cross-block sync — the
// dispatch boundary is the sync.
__global__ void scan_hist_par_kernel(const int* __restrict__ degI, const int* __restrict__ degU,
                                     int* __restrict__ rpI, int* __restrict__ rpU,
                                     int* __restrict__ blkI, int* __restrict__ blkU,
                                     int* __restrict__ histI, int* __restrict__ histU,
                                     int NI, int NU, int BI, int BU, int BI2, int BU2){
  const int tid = threadIdx.x;
  const int b = blockIdx.x;
  const int nscan = BI + BU;
  if (b < nscan){
    __shared__ int s[256];
    const int* deg; int* rowptr; int* blksum; int Nd; int bb;
    if (b < BI){ deg = degI; rowptr = rpI; blksum = blkI; Nd = NI; bb = b; }
    else       { deg = degU; rowptr = rpU; blksum = blkU; Nd = NU; bb = b - BI; }
    const int base = bb * 2048 + tid * 8;
    int v[8]; int tot = 0;
    #pragma unroll
    for (int j = 0; j < 8; j++){
      int idx = base + j;
      v[j] = (idx < Nd) ? deg[idx] : 0;
      tot += v[j];
    }
    s[tid] = tot;
    __syncthreads();
    for (int off = 1; off < 256; off <<= 1){
      int add = (tid >= off) ? s[tid - off] : 0;
      __syncthreads();
      s[tid] += add;
      __syncthreads();
    }
    int run = s[tid] - tot;
    #pragma unroll
    for (int j = 0; j < 8; j++){
      int idx = base + j;
      if (idx < Nd) rowptr[idx] = run;
      run += v[j];
    }
    if (tid == 255) blksum[bb] = s[255];
  } else {
    __shared__ int h2[64];
    if (tid < 64) h2[tid] = 0;
    __syncthreads();
    const int bb = b - nscan;
    const int* deg; int* gh; int base; int N;
    if (bb < BI2){ deg = degI; gh = histI; base = bb * 256; N = NI; }
    else         { deg = degU; gh = histU; base = (bb - BI2) * 256; N = NU; }
    const int n = base + tid;
    if (n < N) atomicAdd(&h2[min(deg[n], 63)], 1);
    __syncthreads();
    if (tid < 64 && h2[tid]) atomicAdd(&gh[tid], h2[tid]);
  }
}

// single block: waves 0-1 do blk top-level exclusive scan; waves 2-3 do hist suffix scan
__global__ void tops_kernel(int* __restrict__ blkI, int BI, int* __restrict__ blkU, int BU,
                            int* __restrict__ histI, int* __restrict__ histU){
  const int tid = threadIdx.x;   // 256
  const int lane = tid & 63;
  if (tid < 128){
    int* blk = (tid < 64) ? blkI : blkU;
    const int B = (tid < 64) ? BI : BU;
    int v = (lane < B) ? blk[lane] : 0;
    const int orig = v;
    #pragma unroll
    for (int off = 1; off < 64; off <<= 1){
      int u = __shfl_up(v, off, 64);
      if (lane >= off) v += u;
    }
    if (lane < B) blk[lane] = v - orig;
  } else {
    int* h = (tid < 192) ? histI : histU;
    int v = h[lane];
    int x = v;
    #pragma unroll
    for (int off = 1; off < 64; off <<= 1){
      int u = __shfl_down(x, off, 64);
      x += (lane + off < 64) ? u : 0;
    }
    h[lane] = x - v;
  }
}

__global__ void scan_add2_kernel(int* __restrict__ rpI, int* __restrict__ rpU,
                                 const int* __restrict__ blkI, const int* __restrict__ blkU,
                                 int* __restrict__ curI, int* __restrict__ curU,
                                 int NI, int NU, int BI, int E){
  const int b = blockIdx.x;
  int* rowptr; const int* blksum; int* curs; int Nd; int bb;
  if (b < BI){ rowptr = rpI; blksum = blkI; curs = curI; Nd = NI; bb = b; }
  else       { rowptr = rpU; blksum = blkU; curs = curU; Nd = NU; bb = b - BI; }
  const int base = bb * 2048 + threadIdx.x * 8;
  const int add = blksum[bb];
  #pragma unroll
  for (int j = 0; j < 8; j++){
    int idx = base + j;
    if (idx < Nd){ int v = rowptr[idx] + add; rowptr[idx] = v; curs[idx] = v; }
    else if (idx == Nd) rowptr[idx] = E;
  }
}

// merged: perm scatter (counting-sort placement) + edge scatter, one dispatch
__global__ void scatter_all_kernel(const int* __restrict__ esrc, const int* __restrict__ edst,
                                   int* __restrict__ curI, int* __restrict__ curU,
                                   int* __restrict__ srcI, int* __restrict__ srcU,
                                   const int* __restrict__ rpI, const int* __restrict__ rpU,
                                   int* __restrict__ histI, int* __restrict__ histU,
                                   int* __restrict__ permI, int* __restrict__ permU,
                                   int NI, int NU, int E, int BI2, int BU2){
  const int tid = threadIdx.x;
  const int b = blockIdx.x;
  const int BP = BI2 + BU2;
  if (b < BP){
    __shared__ int h[64];
    __shared__ int cur[64];
    if (tid < 64) h[tid] = 0;
    __syncthreads();
    const int* rp; int* gh; int* perm; int base; int N;
    if (b < BI2){ rp = rpI; gh = histI; perm = permI; base = b * 256; N = NI; }
    else        { rp = rpU; gh = histU; perm = permU; base = (b - BI2) * 256; N = NU; }
    const int n = base + tid;
    int bk = -1;
    if (n < N){ int d = rp[n + 1] - rp[n]; bk = min(d, 63); atomicAdd(&h[bk], 1); }
    __syncthreads();
    if (tid < 64) cur[tid] = h[tid] ? atomicAdd(&gh[tid], h[tid]) : 0;
    __syncthreads();
    if (n < N){ int r = atomicAdd(&cur[bk], 1); perm[r] = n; }
  } else {
    int t = (b - BP) * 256 + tid;
    if (t < E){
      int d = edst[t];
      int pos = atomicAdd(&curI[d], 1);
      srcI[pos] = esrc[t];
    } else if (t < 2 * E){
      int tt = t - E;
      int d = esrc[tt];
      int pos = atomicAdd(&curU[d], 1);
      srcU[pos] = edst[tt];
    }
  }
}

// ================= fused GATv2: 4 nodes/wave (16 lanes each), degree-sorted =================
// R1-exact structure: single online-softmax state, 1 edge/iter, depth-1.5 prefetch, VGPR ~24.
struct GatRel {
  const unsigned short* zlrS; // source features [Ns][256] bf16 (xl at +0)
  const unsigned short* zlrD; // dest features   [Nd][256] bf16 (xr at +128)
  const int* rowptr;
  const int* srcArr;
  const int* perm;            // degree-sorted node ids (descending)
  const unsigned short* att;  // [128]
  const unsigned short* bias; // [128]
  void* out;
  unsigned long long elem_off;
  int Nd;
  int nw;                     // ceil(Nd/4)
};

__launch_bounds__(256)
__global__ void fused_gat_sorted_kernel(GatRel A, GatRel B, int do_relu,
                                        const int* __restrict__ flag, int final_store)
{
  const int wave = threadIdx.x >> 6;
  const int lane = threadIdx.x & 63;
  const int ql = lane & 15;
  const int quad = lane >> 4;
  int gw = blockIdx.x * 4 + wave;
  GatRel R;
  if (gw < A.nw) R = A;
  else {
    gw -= A.nw;
    if (gw >= B.nw) return;
    R = B;
  }

  const int rank = gw * 4 + quad;
  const bool vnode = rank < R.Nd;
  int d = 0;
  if (vnode) d = R.perm[rank];
  int beg = 0, end = 0;
  if (vnode){ beg = R.rowptr[d]; end = R.rowptr[d + 1]; }
  int md = end - beg;
  md = max(md, __shfl_xor(md, 16, 64));
  md = max(md, __shfl_xor(md, 32, 64));

  const uint4* zlS4 = (const uint4*)R.zlrS;
  // xr row of dest node: dims [8*ql, 8*ql+8)
  uint4 rv = ((const uint4*)R.zlrD)[(size_t)d * 32 + 16 + ql];
  float r[8], a[8];
  {
    const unsigned int* rp = (const unsigned int*)&rv;
    #pragma unroll
    for (int j = 0; j < 4; j++){
      r[2*j]   = __uint_as_float(rp[j] << 16);
      r[2*j+1] = __uint_as_float(rp[j] & 0xffff0000u);
    }
  }
  uint4 av = ((const uint4*)R.att)[ql];
  {
    const unsigned int* ap = (const unsigned int*)&av;
    #pragma unroll
    for (int j = 0; j < 4; j++){
      a[2*j]   = __uint_as_float(ap[j] << 16) * LOGSCALE;
      a[2*j+1] = __uint_as_float(ap[j] & 0xffff0000u) * LOGSCALE;
    }
  }

  float m = -1e30f, s = 0.f;
  float acc[8];
  #pragma unroll
  for (int j = 0; j < 8; j++) acc[j] = 0.f;

  if (md > 0){
    const int* sA = R.srcArr;
    int i1 = 0, i2 = 0;
    if (beg < end)     i1 = sA[beg];
    if (beg + 1 < end) i2 = sA[beg + 1];
    uint4 g0 = zlS4[(size_t)i1 * 32 + ql];

    for (int it = 0; it < md; it++){
      uint4 g1 = zlS4[(size_t)i2 * 32 + ql];     // prefetch row for it+1
      int i3 = 0;
      { int ee = beg + it + 2; if (ee < end) i3 = sA[ee]; }   // prefetch idx for it+2
      const bool valid = (beg + it) < end;

      float x[8];
      const unsigned int* gp = (const unsigned int*)&g0;
      #pragma unroll
      for (int j = 0; j < 4; j++){
        x[2*j]   = __uint_as_float(gp[j] << 16);
        x[2*j+1] = __uint_as_float(gp[j] & 0xffff0000u);
      }
      float p = 0.f;
      #pragma unroll
      for (int j = 0; j < 8; j++){
        float t = x[j] + r[j];
        t = fmaxf(t, 0.2f * t);
        p = fmaf(a[j], t, p);
      }
      p = dpp_red8(p);
      const float pv = valid ? p : -1e30f;

      if (__builtin_expect(__any(pv > m + 8.f), 0)){
        const float mn = fmaxf(m, pv);
        const float scO = EXPX(m - mn);
        const float qv = valid ? EXPX(pv - mn) : 0.f;
        s = fmaf(s, scO, qv);
        #pragma unroll
        for (int j = 0; j < 8; j++) acc[j] = fmaf(acc[j], scO, x[j] * qv);
        m = mn;
      } else {
        const float qv = valid ? EXPX(pv - m) : 0.f;
        s += qv;
        #pragma unroll
        for (int j = 0; j < 8; j++) acc[j] = fmaf(x[j], qv, acc[j]);
      }
      g0 = g1; i2 = i3;
    }
  }

  const float inv = 1.f / (s + 1e-16f);
  uint4 bv = ((const uint4*)R.bias)[ql];
  float o[8];
  {
    const unsigned int* bp = (const unsigned int*)&bv;
    #pragma unroll
    for (int j = 0; j < 4; j++){
      o[2*j]   = fmaf(acc[2*j],   inv, __uint_as_float(bp[j] << 16));
      o[2*j+1] = fmaf(acc[2*j+1], inv, __uint_as_float(bp[j] & 0xffff0000u));
    }
  }
  if (do_relu){
    #pragma unroll
    for (int j = 0; j < 8; j++) o[j] = fmaxf(o[j], 0.f);
  }
  if (!vnode) return;
  const size_t eidx = (size_t)R.elem_off + (size_t)d * HDIM + 8 * ql;
  if (final_store && (*flag != 0)){
    float4 f0 = {o[0], o[1], o[2], o[3]};
    float4 f1 = {o[4], o[5], o[6], o[7]};
    float4* op = (float4*)R.out;
    op[eidx >> 2] = f0;
    op[(eidx >> 2) + 1] = f1;
  } else {
    uint4 w;
    unsigned int* wp = (unsigned int*)&w;
    #pragma unroll
    for (int j = 0; j < 4; j++)
      wp[j] = (unsigned int)f2b(o[2*j]) | ((unsigned int)f2b(o[2*j+1]) << 16);
    ((uint4*)R.out)[eidx >> 3] = w;
  }
}

extern "C" void kernel_launch(void* const* d_in, const int* in_sizes, int n_in,
                              void* d_out, int out_size, void* d_ws, size_t ws_size,
                              hipStream_t stream)
{
  const int* esrc = (const int*)d_in[12];
  const int* edst = (const int*)d_in[13];

  const int NU = in_sizes[0] / 64;    // 100000
  const int NI = in_sizes[1] / 128;   // 20000
  const int E  = in_sizes[12];        // 250000
  const size_t fu = (size_t)NU * HDIM, fi = (size_t)NI * HDIM;

  // ---- workspace carve, 256B-aligned regions
  char* w = (char*)d_ws;
  auto carve = [&](size_t bytes){ char* p = w; w += (bytes + 255) & ~(size_t)255; return p; };
  int* flag = (int*)carve(4);
  unsigned short* Wc = (unsigned short*)carve(49664 * 2);
  unsigned short* P  = (unsigned short*)carve((size_t)P_TOT * 2);
  unsigned short* Bp = (unsigned short*)carve(114688 * 2);
  unsigned short* Bc = (unsigned short*)carve(1024 * 2);
  int* rowptrI = (int*)carve(((size_t)NI + 1) * 4);
  int* rowptrU = (int*)carve(((size_t)NU + 1) * 4);
  int* curs    = (int*)carve(((size_t)NI + NU) * 4);
  int* cursI = curs;
  int* cursU = curs + NI;
  int* blkI = (int*)carve(64 * 4);
  int* blkU = (int*)carve(64 * 4);
  int* hists = (int*)carve(128 * 4);       // histI[64] | histU[64]
  int* histI = hists;
  int* histU = hists + 64;
  int* permI = (int*)carve((size_t)NI * 4);
  int* permU = (int*)carve((size_t)NU * 4);
  int* srcI  = (int*)carve((size_t)E * 4);
  int* srcU  = (int*)carve((size_t)E * 4);
  unsigned short* zlrU = (unsigned short*)carve((size_t)NU * 256 * 2);  // [NU][xl|xr]
  unsigned short* zlrI = (unsigned short*)carve((size_t)NI * 256 * 2);  // [NI][xl|xr]
  (void)ws_size; (void)n_in; (void)out_size; (void)fi;

  unsigned short* stage_zu = (unsigned short*)d_out;          // layer-0 bf16 staging
  unsigned short* stage_zi = (unsigned short*)d_out + fu;
  (void)stage_zi;

  // ---- 1: cvt (+sniff +zero curs/hists +publish flag)
  CvtArgs ca;
  const int srcIdx[10] = {2, 4, 6, 8, 7, 9, 10, 11, 3, 5};
  const int lens[10] = {8192, 16384, 65536, 65536, 512, 512, 512, 512, 128, 128};
  for (int i = 0; i < 10; i++){ ca.src[i] = d_in[srcIdx[i]]; ca.len[i] = lens[i]; }
  ca.xsniff = (const unsigned short*)d_in[0];
  cvt_all_kernel<<<(P_TOT + 255) / 256, 256, 0, stream>>>(ca, P, flag,
                                                          curs, NI + NU, hists, 128);
  // ---- 2: prep
  prep_weights_kernel<<<(49664 + 255) / 256, 256, 0, stream>>>(P, Wc);

  const unsigned short* cWlU0 = Wc;                 // [64,128]
  const unsigned short* cWrU1 = Wc + 8192;          // [64,128]
  const unsigned short* cWlI1 = Wc + 16384;         // [128,128]
  const unsigned short* cWrI0 = Wc + 32768;         // [128,128]

  // ---- 3: permute + bias concat (merged)
  PermBiasArgs pa;
  pa.W0[0] = cWlU0;                 pa.W1[0] = cWrU1;                 pa.KS[0] = 2; pa.base[0] = 0;     pa.n[0] = 16384;
  pa.W0[1] = cWlI1;                 pa.W1[1] = cWrI0;                 pa.KS[1] = 4; pa.base[1] = 16384; pa.n[1] = 32768;
  pa.W0[2] = P + P_WL + 2 * 16384;  pa.W1[2] = P + P_WR + 3 * 16384;  pa.KS[2] = 4; pa.base[2] = 49152; pa.n[2] = 32768;
  pa.W0[3] = P + P_WL + 3 * 16384;  pa.W1[3] = P + P_WR + 2 * 16384;  pa.KS[3] = 4; pa.base[3] = 81920; pa.n[3] = 32768;
  pa.blo[0] = Wc + 49152;         pa.bhi[0] = Wc + 49152 + 128;
  pa.blo[1] = Wc + 49152 + 256;   pa.bhi[1] = Wc + 49152 + 384;
  pa.blo[2] = P + P_BL + 256;     pa.bhi[2] = P + P_BR + 384;
  pa.blo[3] = P + P_BL + 384;     pa.bhi[3] = P + P_BR + 256;
  permute_bias_kernel<<<(114688 + 1024 + 255) / 256, 256, 0, stream>>>(pa, Bp, Bc);
  unsigned short* BpU0 = Bp;
  unsigned short* BpI0 = Bp + 16384;
  unsigned short* BpU1 = Bp + 49152;
  unsigned short* BpI1 = Bp + 81920;

  // ---- 4-8: CSR build + degree sort (5 dispatches, no device fences)
  const int BI = (NI + 2047) / 2048, BU = (NU + 2047) / 2048;
  const int BI2 = (NI + 255) / 256, BU2 = (NU + 255) / 256;
  count_both_kernel<<<(E + 255) / 256, 256, 0, stream>>>(esrc, edst, cursU, cursI, E);
  scan_hist_par_kernel<<<BI + BU + BI2 + BU2, 256, 0, stream>>>(
      cursI, cursU, rowptrI, rowptrU, blkI, blkU, histI, histU,
      NI, NU, BI, BU, BI2, BU2);
  tops_kernel<<<1, 256, 0, stream>>>(blkI, BI, blkU, BU, histI, histU);
  scan_add2_kernel<<<BI + BU, 256, 0, stream>>>(rowptrI, rowptrU, blkI, blkU, cursI, cursU, NI, NU, BI, E);
  scatter_all_kernel<<<BI2 + BU2 + (2 * E + 255) / 256, 256, 0, stream>>>(
      esrc, edst, cursI, cursU, srcI, srcU, rowptrI, rowptrU,
      histI, histU, permI, permU, NI, NU, E, BI2, BU2);

  const int gMU = (NU + 63) / 64, gMI = (NI + 63) / 64;
  const int nwA = (NI + 3) / 4, nwB = (NU + 3) / 4;
  const int gGat = (nwA + nwB + 3) / 4;   // 256-thread blocks = 4 waves

  for (int l = 0; l < 2; l++){
    if (l == 0){
      linear_both_kernel<64, 128><<<gMU + gMI, 256, 0, stream>>>(
          d_in[0], 64, BpU0, Bc, zlrU, NU, gMU,
          d_in[1], 128, BpI0, Bc + 256, zlrI, NI, flag, 1);
    } else {
      linear_both_kernel<128, 128><<<gMU + gMI, 256, 0, stream>>>(
          stage_zu, 128, BpU1, Bc + 512, zlrU, NU, gMU,
          stage_zi, 128, BpI1, Bc + 768, zlrI, NI, flag, 0);
    }
    const int relu = (l == 0);
    const int final_store = (l == 1);

    GatRel A, B;
    // rel 0: user -> item (dst=item)
    A.zlrS = zlrU; A.zlrD = zlrI; A.rowptr = rowptrI; A.srcArr = srcI; A.perm = permI;
    A.att  = P + P_ATT + (l * 2 + 0) * HDIM;
    A.bias = P + P_BIA + (l * 2 + 0) * HDIM;
    A.out = final_store ? d_out : (void*)stage_zu; A.elem_off = fu; A.Nd = NI; A.nw = nwA;
    // rel 1: item -> user (dst=user)
    B.zlrS = zlrI; B.zlrD = zlrU; B.rowptr = rowptrU; B.srcArr = srcU; B.perm = permU;
    B.att  = P + P_ATT + (l * 2 + 1) * HDIM;
    B.bias = P + P_BIA + (l * 2 + 1) * HDIM;
    B.out = final_store ? d_out : (void*)stage_zu; B.elem_off = 0; B.Nd = NU; B.nw = nwB;

    fused_gat_sorted_kernel<<<gGat, 256, 0, stream>>>(A, B, relu, flag, final_store);
  }
}

// Round 9
// 298.376 us; speedup vs baseline: 1.2379x; 1.0094x over previous
//
#include <hip/hip_runtime.h>

#define HDIM 128   // hidden = HEADS*D = 2*64

typedef __attribute__((ext_vector_type(8))) short short8;
typedef __attribute__((ext_vector_type(4))) float float4v;

__device__ __forceinline__ float b2f(unsigned short u){
  return __uint_as_float(((unsigned int)u) << 16);
}
__device__ __forceinline__ unsigned short f2b(float f){
  unsigned int x = __float_as_uint(f);
  x += 0x7fffu + ((x >> 16) & 1u);           // round-to-nearest-even
  return (unsigned short)(x >> 16);
}

#if __has_builtin(__builtin_amdgcn_exp2f)
#define EXPX(x) __builtin_amdgcn_exp2f(x)
#define LOGSCALE 1.4426950408889634f
#else
#define EXPX(x) __expf(x)
#define LOGSCALE 1.f
#endif

// sum over each 8-lane group (dims of one head) — pure-VALU DPP tree, no LDS pipe
__device__ __forceinline__ float dpp_red8(float x){
  x += __int_as_float(__builtin_amdgcn_update_dpp(0, __float_as_int(x), 0xB1, 0xF, 0xF, true));  // quad_perm xor1
  x += __int_as_float(__builtin_amdgcn_update_dpp(0, __float_as_int(x), 0x4E, 0xF, 0xF, true));  // quad_perm xor2
  x += __int_as_float(__builtin_amdgcn_update_dpp(0, __float_as_int(x), 0x141, 0xF, 0xF, true)); // row_half_mirror
  return x;
}

// per-block redundant dtype sniff (reads 4 KB of x; L2-hot after first block)
__device__ __forceinline__ int sniff_block(const unsigned short* __restrict__ x){
  const int tid = threadIdx.x;               // 256 threads
  int cnt = 0, tot = 0;
  for (int i = tid * 2; i < 4096; i += 512){
    float v = fabsf(b2f(x[i]));
    tot++;
    if (v > 1e-4f && v < 50.f) cnt++;
  }
  __shared__ int s_cnt[256], s_tot[256];
  s_cnt[tid] = cnt; s_tot[tid] = tot;
  __syncthreads();
  for (int o = 128; o > 0; o >>= 1){
    if (tid < o){ s_cnt[tid] += s_cnt[tid + o]; s_tot[tid] += s_tot[tid + o]; }
    __syncthreads();
  }
  __shared__ int res;
  if (tid == 0) res = (s_cnt[0] * 2 < s_tot[0]) ? 1 : 0;
  __syncthreads();
  return res;
}

// canonical params layout (ushort offsets into P)
#define P_WPU 0
#define P_WPI 8192
#define P_WL  24576
#define P_WR  90112
#define P_BL  155648
#define P_BR  156160
#define P_ATT 156672
#define P_BIA 157184
#define P_BPU 157696
#define P_BPI 157824
#define P_TOT 157952

struct CvtArgs { const void* src[10]; int len[10]; const unsigned short* xsniff; };

// cvt + inline sniff + zero scratch (curs, hists) + publish flag
__global__ void cvt_all_kernel(CvtArgs args, unsigned short* __restrict__ P,
                               int* __restrict__ flag,
                               int* __restrict__ zero1, int nz1,
                               int* __restrict__ zero2, int nz2){
  const int f32 = sniff_block(args.xsniff);
  int t = blockIdx.x * 256 + threadIdx.x;
  if (t < nz1) zero1[t] = 0;
  if (t < nz2) zero2[t] = 0;
  if (t == 0) flag[0] = f32;
  if (t >= P_TOT) return;
  int local = t;
  int i = 0;
  while (local >= args.len[i]){ local -= args.len[i]; i++; }
  if (f32) P[t] = f2b(((const float*)args.src[i])[local]);
  else     P[t] = ((const unsigned short*)args.src[i])[local];
}

// ---------------- prep: compose layer-0 weights  Wc = Wp @ W  (+ bp @ W + b)
__global__ void prep_weights_kernel(const unsigned short* __restrict__ P,
                                    unsigned short* __restrict__ Wc)
{
  const int t = blockIdx.x * 256 + threadIdx.x;
  if (t >= 49664) return;
  const unsigned short* Wl = P + P_WL;
  const unsigned short* Wr = P + P_WR;
  const unsigned short* Bm[4] = { Wl, Wr + 16384, Wl + 16384, Wr };
  const unsigned short* Av[4] = { P + P_WPU, P + P_WPU, P + P_WPI, P + P_WPI };
  const unsigned short* bv[4] = { P + P_BPU, P + P_BPU, P + P_BPI, P + P_BPI };
  const unsigned short* bo[4] = { P + P_BL, P + P_BR + 128, P + P_BL + 128, P + P_BR };
  if (t < 49152){
    int job, base;
    if (t < 8192)       { job = 0; base = 0; }
    else if (t < 16384) { job = 1; base = 8192; }
    else if (t < 32768) { job = 2; base = 16384; }
    else                { job = 3; base = 32768; }
    const int local = t - base;
    const int k = local >> 7, n = local & 127;
    const unsigned short* A = Av[job] + (size_t)k * 128;
    const unsigned short* B = Bm[job];
    float s = 0.f;
    #pragma unroll 4
    for (int h = 0; h < 128; h++) s = fmaf(b2f(A[h]), b2f(B[h * 128 + n]), s);
    Wc[t] = f2b(s);
  } else {
    const int local = t - 49152;
    const int job = local >> 7, n = local & 127;
    const unsigned short* B = Bm[job];
    float s = b2f(bo[job][n]);
    for (int h = 0; h < 128; h++) s = fmaf(b2f(bv[job][h]), b2f(B[h * 128 + n]), s);
    Wc[t] = f2b(s);
  }
}

// ---------------- permute all 4 concat weights into B-fragment order + concat biases (merged)
struct PermBiasArgs { const unsigned short* W0[4]; const unsigned short* W1[4];
                      int KS[4]; int base[4]; int n[4];
                      const unsigned short* blo[4]; const unsigned short* bhi[4]; };
__global__ void permute_bias_kernel(PermBiasArgs pa, unsigned short* __restrict__ dst,
                                    unsigned short* __restrict__ dstB){
  int t = blockIdx.x * 256 + threadIdx.x;
  if (t >= 114688){
    int u = t - 114688;
    if (u < 1024){
      int set = u >> 8, c = u & 255;
      dstB[u] = (c < 128) ? pa.blo[set][c] : pa.bhi[set][c - 128];
    }
    return;
  }
  int job = 0;
  while (job < 4 && t >= pa.base[job] + pa.n[job]) job++;
  if (job >= 4) return;
  int local = t - pa.base[job];
  int KS = pa.KS[job];
  int j = local & 7, rest = local >> 3;
  int l = rest & 63; rest >>= 6;
  int ks = rest % KS, tile = rest / KS;
  int k = ks * 32 + (l >> 4) * 8 + j;
  int c = tile * 16 + (l & 15);
  dst[t] = (c < 128) ? pa.W0[job][k * 128 + c] : pa.W1[job][k * 128 + (c - 128)];
}

// ---------------- MFMA linear: 32-row tiles (2x grid, ~half VGPR/LDS vs 64-row).
// A-tile staged through LDS (coalesced); LDS row stride K+8 keeps 16B alignment.
template<int K>
__device__ __forceinline__ void linear_body(const void* __restrict__ Xv, int xstride,
                                            bool f32,
                                            const unsigned short* __restrict__ Bp,
                                            const unsigned short* __restrict__ bias,
                                            unsigned short* __restrict__ Y, int M, int bx,
                                            unsigned short* __restrict__ lds)
{
  constexpr int KS = K / 32;
  constexpr int LK = K + 8;                  // padded LDS row stride (ushorts)
  constexpr int ROUNDS = (32 * K) / 2048;    // 1 for K=64, 2 for K=128
  const int wave = threadIdx.x >> 6, lane = threadIdx.x & 63;
  const int quad = lane >> 4, l16 = lane & 15;
  const int row0 = bx * 32;

  // ---- stage A tile [32][K] -> LDS, coalesced (8 elems / thread / round)
  #pragma unroll
  for (int rd = 0; rd < ROUNDS; rd++){
    const int e = rd * 2048 + (int)threadIdx.x * 8;
    const int rr = e / K, cc = e % K;        // K is power of two
    int grow = row0 + rr; if (grow >= M) grow = M - 1;
    unsigned short* dst = lds + rr * LK + cc;
    if (f32){
      const float* p = (const float*)Xv + (size_t)grow * xstride + cc;
      float4 v0 = *(const float4*)p;
      float4 v1 = *(const float4*)(p + 4);
      short8 tmp;
      tmp[0] = (short)f2b(v0.x); tmp[1] = (short)f2b(v0.y);
      tmp[2] = (short)f2b(v0.z); tmp[3] = (short)f2b(v0.w);
      tmp[4] = (short)f2b(v1.x); tmp[5] = (short)f2b(v1.y);
      tmp[6] = (short)f2b(v1.z); tmp[7] = (short)f2b(v1.w);
      *(short8*)dst = tmp;
    } else {
      *(short8*)dst = *(const short8*)((const unsigned short*)Xv + (size_t)grow * xstride + cc);
    }
  }
  __syncthreads();

  float4v acc[2][4];
  const float4v z = {0.f, 0.f, 0.f, 0.f};
  #pragma unroll
  for (int i = 0; i < 2; i++)
    #pragma unroll
    for (int j = 0; j < 4; j++) acc[i][j] = z;

  #pragma unroll
  for (int ks = 0; ks < KS; ks++){
    const int col = ks * 32 + quad * 8;
    short8 a[2];
    #pragma unroll
    for (int mt = 0; mt < 2; mt++)
      a[mt] = *(const short8*)(lds + (mt * 16 + l16) * LK + col);   // ds_read_b128, 2-way
    short8 b[4];
    #pragma unroll
    for (int ntl = 0; ntl < 4; ntl++){
      const int t = wave * 4 + ntl;
      b[ntl] = *(const short8*)(Bp + ((size_t)(t * KS + ks) * 64 + lane) * 8);
    }
    #pragma unroll
    for (int mt = 0; mt < 2; mt++)
      #pragma unroll
      for (int ntl = 0; ntl < 4; ntl++)
        acc[mt][ntl] = __builtin_amdgcn_mfma_f32_16x16x32_bf16(a[mt], b[ntl], acc[mt][ntl], 0, 0, 0);
  }

  #pragma unroll
  for (int mt = 0; mt < 2; mt++){
    #pragma unroll
    for (int ntl = 0; ntl < 4; ntl++){
      const int t = wave * 4 + ntl;
      const int colb = t * 16 + l16;
      const float bb = b2f(bias[colb]);
      #pragma unroll
      for (int r = 0; r < 4; r++){
        const int row = row0 + mt * 16 + quad * 4 + r;
        if (row < M) Y[(size_t)row * 256 + colb] = f2b(acc[mt][ntl][r] + bb);
      }
    }
  }
}

template<int KA, int KB>
__launch_bounds__(256)
__global__ void linear_both_kernel(const void* __restrict__ XA, int sA,
                                   const unsigned short* __restrict__ BpA,
                                   const unsigned short* __restrict__ biasA,
                                   unsigned short* __restrict__ YA, int MA, int gA,
                                   const void* __restrict__ XB, int sB,
                                   const unsigned short* __restrict__ BpB,
                                   const unsigned short* __restrict__ biasB,
                                   unsigned short* __restrict__ YB, int MB,
                                   const int* __restrict__ flag, int use_flag)
{
  __shared__ unsigned short lds[32 * 136];     // max K=128 padded: 8704 B
  const bool f32 = use_flag && (*flag != 0);
  if ((int)blockIdx.x < gA) linear_body<KA>(XA, sA, f32, BpA, biasA, YA, MA, blockIdx.x, lds);
  else                      linear_body<KB>(XB, sB, f32, BpB, biasB, YB, MB, blockIdx.x - gA, lds);
}

// ================= CSR build =================
__global__ void count_both_kernel(const int* __restrict__ esrc, const int* __restrict__ edst,
                                  int* __restrict__ degU, int* __restrict__ degI, int E){
  int t = blockIdx.x * 256 + threadIdx.x;
  if (t >= E) return;
  atomicAdd(&degI[edst[t]], 1);
  atomicAdd(&degU[esrc[t]], 1);
}

// block-parallel: per-block scan || degree histogram. NO cross-block sync — the
// dispatch boundary is the sync.
__global__ void scan_hist_par_kernel(const int* __restrict__ degI, const int* __restrict__ degU,
                                     int* __restrict__ rpI, int* __restrict__ rpU,
                                     int* __restrict__ blkI, int* __restrict__ blkU,
                                     int* __restrict__ histI, int* __restrict__ histU,
                                     int NI, int NU, int BI, int BU, int BI2, int BU2){
  const int tid = threadIdx.x;
  const int b = blockIdx.x;
  const int nscan = BI + BU;
  if (b < nscan){
    __shared__ int s[256];
    const int* deg; int* rowptr; int* blksum; int Nd; int bb;
    if (b < BI){ deg = degI; rowptr = rpI; blksum = blkI; Nd = NI; bb = b; }
    else       { deg = degU; rowptr = rpU; blksum = blkU; Nd = NU; bb = b - BI; }
    const int base = bb * 2048 + tid * 8;
    int v[8]; int tot = 0;
    #pragma unroll
    for (int j = 0; j < 8; j++){
      int idx = base + j;
      v[j] = (idx < Nd) ? deg[idx] : 0;
      tot += v[j];
    }
    s[tid] = tot;
    __syncthreads();
    for (int off = 1; off < 256; off <<= 1){
      int add = (tid >= off) ? s[tid - off] : 0;
      __syncthreads();
      s[tid] += add;
      __syncthreads();
    }
    int run = s[tid] - tot;
    #pragma unroll
    for (int j = 0; j < 8; j++){
      int idx = base + j;
      if (idx < Nd) rowptr[idx] = run;
      run += v[j];
    }
    if (tid == 255) blksum[bb] = s[255];
  } else {
    __shared__ int h2[64];
    if (tid < 64) h2[tid] = 0;
    __syncthreads();
    const int bb = b - nscan;
    const int* deg; int* gh; int base; int N;
    if (bb < BI2){ deg = degI; gh = histI; base = bb * 256; N = NI; }
    else         { deg = degU; gh = histU; base = (bb - BI2) * 256; N = NU; }
    const int n = base + tid;
    if (n < N) atomicAdd(&h2[min(deg[n], 63)], 1);
    __syncthreads();
    if (tid < 64 && h2[tid]) atomicAdd(&gh[tid], h2[tid]);
  }
}

// single block: waves 0-1 do blk top-level exclusive scan; waves 2-3 do hist suffix scan
__global__ void tops_kernel(int* __restrict__ blkI, int BI, int* __restrict__ blkU, int BU,
                            int* __restrict__ histI, int* __restrict__ histU){
  const int tid = threadIdx.x;   // 256
  const int lane = tid & 63;
  if (tid < 128){
    int* blk = (tid < 64) ? blkI : blkU;
    const int B = (tid < 64) ? BI : BU;
    int v = (lane < B) ? blk[lane] : 0;
    const int orig = v;
    #pragma unroll
    for (int off = 1; off < 64; off <<= 1){
      int u = __shfl_up(v, off, 64);
      if (lane >= off) v += u;
    }
    if (lane < B) blk[lane] = v - orig;
  } else {
    int* h = (tid < 192) ? histI : histU;
    int v = h[lane];
    int x = v;
    #pragma unroll
    for (int off = 1; off < 64; off <<= 1){
      int u = __shfl_down(x, off, 64);
      x += (lane + off < 64) ? u : 0;
    }
    h[lane] = x - v;
  }
}

__global__ void scan_add2_kernel(int* __restrict__ rpI, int* __restrict__ rpU,
                                 const int* __restrict__ blkI, const int* __restrict__ blkU,
                                 int* __restrict__ curI, int* __restrict__ curU,
                                 int NI, int NU, int BI, int E){
  const int b = blockIdx.x;
  int* rowptr; const int* blksum; int* curs; int Nd; int bb;
  if (b < BI){ rowptr = rpI; blksum = blkI; curs = curI; Nd = NI; bb = b; }
  else       { rowptr = rpU; blksum = blkU; curs = curU; Nd = NU; bb = b - BI; }
  const int base = bb * 2048 + threadIdx.x * 8;
  const int add = blksum[bb];
  #pragma unroll
  for (int j = 0; j < 8; j++){
    int idx = base + j;
    if (idx < Nd){ int v = rowptr[idx] + add; rowptr[idx] = v; curs[idx] = v; }
    else if (idx == Nd) rowptr[idx] = E;
  }
}

// merged: perm scatter (counting-sort placement) + edge scatter, one dispatch
__global__ void scatter_all_kernel(const int* __restrict__ esrc, const int* __restrict__ edst,
                                   int* __restrict__ curI, int* __restrict__ curU,
                                   int* __restrict__ srcI, int* __restrict__ srcU,
                                   const int* __restrict__ rpI, const int* __restrict__ rpU,
                                   int* __restrict__ histI, int* __restrict__ histU,
                                   int* __restrict__ permI, int* __restrict__ permU,
                                   int NI, int NU, int E, int BI2, int BU2){
  const int tid = threadIdx.x;
  const int b = blockIdx.x;
  const int BP = BI2 + BU2;
  if (b < BP){
    __shared__ int h[64];
    __shared__ int cur[64];
    if (tid < 64) h[tid] = 0;
    __syncthreads();
    const int* rp; int* gh; int* perm; int base; int N;
    if (b < BI2){ rp = rpI; gh = histI; perm = permI; base = b * 256; N = NI; }
    else        { rp = rpU; gh = histU; perm = permU; base = (b - BI2) * 256; N = NU; }
    const int n = base + tid;
    int bk = -1;
    if (n < N){ int d = rp[n + 1] - rp[n]; bk = min(d, 63); atomicAdd(&h[bk], 1); }
    __syncthreads();
    if (tid < 64) cur[tid] = h[tid] ? atomicAdd(&gh[tid], h[tid]) : 0;
    __syncthreads();
    if (n < N){ int r = atomicAdd(&cur[bk], 1); perm[r] = n; }
  } else {
    int t = (b - BP) * 256 + tid;
    if (t < E){
      int d = edst[t];
      int pos = atomicAdd(&curI[d], 1);
      srcI[pos] = esrc[t];
    } else if (t < 2 * E){
      int tt = t - E;
      int d = esrc[tt];
      int pos = atomicAdd(&curU[d], 1);
      srcU[pos] = edst[tt];
    }
  }
}

// ================= fused GATv2: 4 nodes/wave (16 lanes each), degree-sorted =================
// R1-exact structure: single online-softmax state, 1 edge/iter, depth-1.5 prefetch, VGPR ~24.
struct GatRel {
  const unsigned short* zlrS; // source features [Ns][256] bf16 (xl at +0)
  const unsigned short* zlrD; // dest features   [Nd][256] bf16 (xr at +128)
  const int* rowptr;
  const int* srcArr;
  const int* perm;            // degree-sorted node ids (descending)
  const unsigned short* att;  // [128]
  const unsigned short* bias; // [128]
  void* out;
  unsigned long long elem_off;
  int Nd;
  int nw;                     // ceil(Nd/4)
};

__launch_bounds__(256)
__global__ void fused_gat_sorted_kernel(GatRel A, GatRel B, int do_relu,
                                        const int* __restrict__ flag, int final_store)
{
  const int wave = threadIdx.x >> 6;
  const int lane = threadIdx.x & 63;
  const int ql = lane & 15;
  const int quad = lane >> 4;
  int gw = blockIdx.x * 4 + wave;
  GatRel R;
  if (gw < A.nw) R = A;
  else {
    gw -= A.nw;
    if (gw >= B.nw) return;
    R = B;
  }

  const int rank = gw * 4 + quad;
  const bool vnode = rank < R.Nd;
  int d = 0;
  if (vnode) d = R.perm[rank];
  int beg = 0, end = 0;
  if (vnode){ beg = R.rowptr[d]; end = R.rowptr[d + 1]; }
  int md = end - beg;
  md = max(md, __shfl_xor(md, 16, 64));
  md = max(md, __shfl_xor(md, 32, 64));

  const uint4* zlS4 = (const uint4*)R.zlrS;
  // xr row of dest node: dims [8*ql, 8*ql+8)
  uint4 rv = ((const uint4*)R.zlrD)[(size_t)d * 32 + 16 + ql];
  float r[8], a[8];
  {
    const unsigned int* rp = (const unsigned int*)&rv;
    #pragma unroll
    for (int j = 0; j < 4; j++){
      r[2*j]   = __uint_as_float(rp[j] << 16);
      r[2*j+1] = __uint_as_float(rp[j] & 0xffff0000u);
    }
  }
  uint4 av = ((const uint4*)R.att)[ql];
  {
    const unsigned int* ap = (const unsigned int*)&av;
    #pragma unroll
    for (int j = 0; j < 4; j++){
      a[2*j]   = __uint_as_float(ap[j] << 16) * LOGSCALE;
      a[2*j+1] = __uint_as_float(ap[j] & 0xffff0000u) * LOGSCALE;
    }
  }

  float m = -1e30f, s = 0.f;
  float acc[8];
  #pragma unroll
  for (int j = 0; j < 8; j++) acc[j] = 0.f;

  if (md > 0){
    const int* sA = R.srcArr;
    int i1 = 0, i2 = 0;
    if (beg < end)     i1 = sA[beg];
    if (beg + 1 < end) i2 = sA[beg + 1];
    uint4 g0 = zlS4[(size_t)i1 * 32 + ql];

    for (int it = 0; it < md; it++){
      uint4 g1 = zlS4[(size_t)i2 * 32 + ql];     // prefetch row for it+1
      int i3 = 0;
      { int ee = beg + it + 2; if (ee < end) i3 = sA[ee]; }   // prefetch idx for it+2
      const bool valid = (beg + it) < end;

      float x[8];
      const unsigned int* gp = (const unsigned int*)&g0;
      #pragma unroll
      for (int j = 0; j < 4; j++){
        x[2*j]   = __uint_as_float(gp[j] << 16);
        x[2*j+1] = __uint_as_float(gp[j] & 0xffff0000u);
      }
      float p = 0.f;
      #pragma unroll
      for (int j = 0; j < 8; j++){
        float t = x[j] + r[j];
        t = fmaxf(t, 0.2f * t);
        p = fmaf(a[j], t, p);
      }
      p = dpp_red8(p);
      const float pv = valid ? p : -1e30f;

      if (__builtin_expect(__any(pv > m + 8.f), 0)){
        const float mn = fmaxf(m, pv);
        const float scO = EXPX(m - mn);
        const float qv = valid ? EXPX(pv - mn) : 0.f;
        s = fmaf(s, scO, qv);
        #pragma unroll
        for (int j = 0; j < 8; j++) acc[j] = fmaf(acc[j], scO, x[j] * qv);
        m = mn;
      } else {
        const float qv = valid ? EXPX(pv - m) : 0.f;
        s += qv;
        #pragma unroll
        for (int j = 0; j < 8; j++) acc[j] = fmaf(x[j], qv, acc[j]);
      }
      g0 = g1; i2 = i3;
    }
  }

  const float inv = 1.f / (s + 1e-16f);
  uint4 bv = ((const uint4*)R.bias)[ql];
  float o[8];
  {
    const unsigned int* bp = (const unsigned int*)&bv;
    #pragma unroll
    for (int j = 0; j < 4; j++){
      o[2*j]   = fmaf(acc[2*j],   inv, __uint_as_float(bp[j] << 16));
      o[2*j+1] = fmaf(acc[2*j+1], inv, __uint_as_float(bp[j] & 0xffff0000u));
    }
  }
  if (do_relu){
    #pragma unroll
    for (int j = 0; j < 8; j++) o[j] = fmaxf(o[j], 0.f);
  }
  if (!vnode) return;
  const size_t eidx = (size_t)R.elem_off + (size_t)d * HDIM + 8 * ql;
  if (final_store && (*flag != 0)){
    float4 f0 = {o[0], o[1], o[2], o[3]};
    float4 f1 = {o[4], o[5], o[6], o[7]};
    float4* op = (float4*)R.out;
    op[eidx >> 2] = f0;
    op[(eidx >> 2) + 1] = f1;
  } else {
    uint4 w;
    unsigned int* wp = (unsigned int*)&w;
    #pragma unroll
    for (int j = 0; j < 4; j++)
      wp[j] = (unsigned int)f2b(o[2*j]) | ((unsigned int)f2b(o[2*j+1]) << 16);
    ((uint4*)R.out)[eidx >> 3] = w;
  }
}

extern "C" void kernel_launch(void* const* d_in, const int* in_sizes, int n_in,
                              void* d_out, int out_size, void* d_ws, size_t ws_size,
                              hipStream_t stream)
{
  const int* esrc = (const int*)d_in[12];
  const int* edst = (const int*)d_in[13];

  const int NU = in_sizes[0] / 64;    // 100000
  const int NI = in_sizes[1] / 128;   // 20000
  const int E  = in_sizes[12];        // 250000
  const size_t fu = (size_t)NU * HDIM, fi = (size_t)NI * HDIM;

  // ---- workspace carve, 256B-aligned regions
  char* w = (char*)d_ws;
  auto carve = [&](size_t bytes){ char* p = w; w += (bytes + 255) & ~(size_t)255; return p; };
  int* flag = (int*)carve(4);
  unsigned short* Wc = (unsigned short*)carve(49664 * 2);
  unsigned short* P  = (unsigned short*)carve((size_t)P_TOT * 2);
  unsigned short* Bp = (unsigned short*)carve(114688 * 2);
  unsigned short* Bc = (unsigned short*)carve(1024 * 2);
  int* rowptrI = (int*)carve(((size_t)NI + 1) * 4);
  int* rowptrU = (int*)carve(((size_t)NU + 1) * 4);
  int* curs    = (int*)carve(((size_t)NI + NU) * 4);
  int* cursI = curs;
  int* cursU = curs + NI;
  int* blkI = (int*)carve(64 * 4);
  int* blkU = (int*)carve(64 * 4);
  int* hists = (int*)carve(128 * 4);       // histI[64] | histU[64]
  int* histI = hists;
  int* histU = hists + 64;
  int* permI = (int*)carve((size_t)NI * 4);
  int* permU = (int*)carve((size_t)NU * 4);
  int* srcI  = (int*)carve((size_t)E * 4);
  int* srcU  = (int*)carve((size_t)E * 4);
  unsigned short* zlrU = (unsigned short*)carve((size_t)NU * 256 * 2);  // [NU][xl|xr]
  unsigned short* zlrI = (unsigned short*)carve((size_t)NI * 256 * 2);  // [NI][xl|xr]
  (void)ws_size; (void)n_in; (void)out_size; (void)fi;

  unsigned short* stage_zu = (unsigned short*)d_out;          // layer-0 bf16 staging
  unsigned short* stage_zi = (unsigned short*)d_out + fu;
  (void)stage_zi;

  // ---- 1: cvt (+sniff +zero curs/hists +publish flag)
  CvtArgs ca;
  const int srcIdx[10] = {2, 4, 6, 8, 7, 9, 10, 11, 3, 5};
  const int lens[10] = {8192, 16384, 65536, 65536, 512, 512, 512, 512, 128, 128};
  for (int i = 0; i < 10; i++){ ca.src[i] = d_in[srcIdx[i]]; ca.len[i] = lens[i]; }
  ca.xsniff = (const unsigned short*)d_in[0];
  cvt_all_kernel<<<(P_TOT + 255) / 256, 256, 0, stream>>>(ca, P, flag,
                                                          curs, NI + NU, hists, 128);
  // ---- 2: prep
  prep_weights_kernel<<<(49664 + 255) / 256, 256, 0, stream>>>(P, Wc);

  const unsigned short* cWlU0 = Wc;                 // [64,128]
  const unsigned short* cWrU1 = Wc + 8192;          // [64,128]
  const unsigned short* cWlI1 = Wc + 16384;         // [128,128]
  const unsigned short* cWrI0 = Wc + 32768;         // [128,128]

  // ---- 3: permute + bias concat (merged)
  PermBiasArgs pa;
  pa.W0[0] = cWlU0;                 pa.W1[0] = cWrU1;                 pa.KS[0] = 2; pa.base[0] = 0;     pa.n[0] = 16384;
  pa.W0[1] = cWlI1;                 pa.W1[1] = cWrI0;                 pa.KS[1] = 4; pa.base[1] = 16384; pa.n[1] = 32768;
  pa.W0[2] = P + P_WL + 2 * 16384;  pa.W1[2] = P + P_WR + 3 * 16384;  pa.KS[2] = 4; pa.base[2] = 49152; pa.n[2] = 32768;
  pa.W0[3] = P + P_WL + 3 * 16384;  pa.W1[3] = P + P_WR + 2 * 16384;  pa.KS[3] = 4; pa.base[3] = 81920; pa.n[3] = 32768;
  pa.blo[0] = Wc + 49152;         pa.bhi[0] = Wc + 49152 + 128;
  pa.blo[1] = Wc + 49152 + 256;   pa.bhi[1] = Wc + 49152 + 384;
  pa.blo[2] = P + P_BL + 256;     pa.bhi[2] = P + P_BR + 384;
  pa.blo[3] = P + P_BL + 384;     pa.bhi[3] = P + P_BR + 256;
  permute_bias_kernel<<<(114688 + 1024 + 255) / 256, 256, 0, stream>>>(pa, Bp, Bc);
  unsigned short* BpU0 = Bp;
  unsigned short* BpI0 = Bp + 16384;
  unsigned short* BpU1 = Bp + 49152;
  unsigned short* BpI1 = Bp + 81920;

  // ---- 4-8: CSR build + degree sort (5 dispatches, no device fences)
  const int BI = (NI + 2047) / 2048, BU = (NU + 2047) / 2048;
  const int BI2 = (NI + 255) / 256, BU2 = (NU + 255) / 256;
  count_both_kernel<<<(E + 255) / 256, 256, 0, stream>>>(esrc, edst, cursU, cursI, E);
  scan_hist_par_kernel<<<BI + BU + BI2 + BU2, 256, 0, stream>>>(
      cursI, cursU, rowptrI, rowptrU, blkI, blkU, histI, histU,
      NI, NU, BI, BU, BI2, BU2);
  tops_kernel<<<1, 256, 0, stream>>>(blkI, BI, blkU, BU, histI, histU);
  scan_add2_kernel<<<BI + BU, 256, 0, stream>>>(rowptrI, rowptrU, blkI, blkU, cursI, cursU, NI, NU, BI, E);
  scatter_all_kernel<<<BI2 + BU2 + (2 * E + 255) / 256, 256, 0, stream>>>(
      esrc, edst, cursI, cursU, srcI, srcU, rowptrI, rowptrU,
      histI, histU, permI, permU, NI, NU, E, BI2, BU2);

  const int gMU = (NU + 31) / 32, gMI = (NI + 31) / 32;
  const int nwA = (NI + 3) / 4, nwB = (NU + 3) / 4;
  const int gGat = (nwA + nwB + 3) / 4;   // 256-thread blocks = 4 waves

  for (int l = 0; l < 2; l++){
    if (l == 0){
      linear_both_kernel<64, 128><<<gMU + gMI, 256, 0, stream>>>(
          d_in[0], 64, BpU0, Bc, zlrU, NU, gMU,
          d_in[1], 128, BpI0, Bc + 256, zlrI, NI, flag, 1);
    } else {
      linear_both_kernel<128, 128><<<gMU + gMI, 256, 0, stream>>>(
          stage_zu, 128, BpU1, Bc + 512, zlrU, NU, gMU,
          stage_zi, 128, BpI1, Bc + 768, zlrI, NI, flag, 0);
    }
    const int relu = (l == 0);
    const int final_store = (l == 1);

    GatRel A, B;
    // rel 0: user -> item (dst=item)
    A.zlrS = zlrU; A.zlrD = zlrI; A.rowptr = rowptrI; A.srcArr = srcI; A.perm = permI;
    A.att  = P + P_ATT + (l * 2 + 0) * HDIM;
    A.bias = P + P_BIA + (l * 2 + 0) * HDIM;
    A.out = final_store ? d_out : (void*)stage_zu; A.elem_off = fu; A.Nd = NI; A.nw = nwA;
    // rel 1: item -> user (dst=user)
    B.zlrS = zlrI; B.zlrD = zlrU; B.rowptr = rowptrU; B.srcArr = srcU; B.perm = permU;
    B.att  = P + P_ATT + (l * 2 + 1) * HDIM;
    B.bias = P + P_BIA + (l * 2 + 1) * HDIM;
    B.out = final_store ? d_out : (void*)stage_zu; B.elem_off = 0; B.Nd = NU; B.nw = nwB;

    fused_gat_sorted_kernel<<<gGat, 256, 0, stream>>>(A, B, relu, flag, final_store);
  }
}

// Round 10
// 292.529 us; speedup vs baseline: 1.2627x; 1.0200x over previous
//
#include <hip/hip_runtime.h>

#define HDIM 128   // hidden = HEADS*D = 2*64

typedef __attribute__((ext_vector_type(8))) short short8;
typedef __attribute__((ext_vector_type(4))) float float4v;

__device__ __forceinline__ float b2f(unsigned short u){
  return __uint_as_float(((unsigned int)u) << 16);
}
__device__ __forceinline__ unsigned short f2b(float f){
  unsigned int x = __float_as_uint(f);
  x += 0x7fffu + ((x >> 16) & 1u);           // round-to-nearest-even
  return (unsigned short)(x >> 16);
}

#if __has_builtin(__builtin_amdgcn_exp2f)
#define EXPX(x) __builtin_amdgcn_exp2f(x)
#define LOGSCALE 1.4426950408889634f
#else
#define EXPX(x) __expf(x)
#define LOGSCALE 1.f
#endif

// sum over each 8-lane group (dims of one head) — pure-VALU DPP tree, no LDS pipe
__device__ __forceinline__ float dpp_red8(float x){
  x += __int_as_float(__builtin_amdgcn_update_dpp(0, __float_as_int(x), 0xB1, 0xF, 0xF, true));  // quad_perm xor1
  x += __int_as_float(__builtin_amdgcn_update_dpp(0, __float_as_int(x), 0x4E, 0xF, 0xF, true));  // quad_perm xor2
  x += __int_as_float(__builtin_amdgcn_update_dpp(0, __float_as_int(x), 0x141, 0xF, 0xF, true)); // row_half_mirror
  return x;
}

// per-block redundant dtype sniff (reads 4 KB of x; L2-hot after first block)
__device__ __forceinline__ int sniff_block(const unsigned short* __restrict__ x){
  const int tid = threadIdx.x;               // 256 threads
  int cnt = 0, tot = 0;
  for (int i = tid * 2; i < 4096; i += 512){
    float v = fabsf(b2f(x[i]));
    tot++;
    if (v > 1e-4f && v < 50.f) cnt++;
  }
  __shared__ int s_cnt[256], s_tot[256];
  s_cnt[tid] = cnt; s_tot[tid] = tot;
  __syncthreads();
  for (int o = 128; o > 0; o >>= 1){
    if (tid < o){ s_cnt[tid] += s_cnt[tid + o]; s_tot[tid] += s_tot[tid + o]; }
    __syncthreads();
  }
  __shared__ int res;
  if (tid == 0) res = (s_cnt[0] * 2 < s_tot[0]) ? 1 : 0;
  __syncthreads();
  return res;
}

// canonical params layout (ushort offsets into P)
#define P_WPU 0
#define P_WPI 8192
#define P_WL  24576
#define P_WR  90112
#define P_BL  155648
#define P_BR  156160
#define P_ATT 156672
#define P_BIA 157184
#define P_BPU 157696
#define P_BPI 157824
#define P_TOT 157952

struct CvtArgs { const void* src[10]; int len[10]; const unsigned short* xsniff; };

// cvt + inline sniff + zero scratch (curs, hists+cursors) + publish flag
__global__ void cvt_all_kernel(CvtArgs args, unsigned short* __restrict__ P,
                               int* __restrict__ flag,
                               int* __restrict__ zero1, int nz1,
                               int* __restrict__ zero2, int nz2){
  const int f32 = sniff_block(args.xsniff);
  int t = blockIdx.x * 256 + threadIdx.x;
  if (t < nz1) zero1[t] = 0;
  if (t < nz2) zero2[t] = 0;
  if (t == 0) flag[0] = f32;
  if (t >= P_TOT) return;
  int local = t;
  int i = 0;
  while (local >= args.len[i]){ local -= args.len[i]; i++; }
  if (f32) P[t] = f2b(((const float*)args.src[i])[local]);
  else     P[t] = ((const unsigned short*)args.src[i])[local];
}

// ---------------- prep (compose layer-0 weights) + edge-degree count, one dispatch
// both parts depend only on cvt; disjoint block ranges.
__global__ void prep_count_kernel(const unsigned short* __restrict__ P,
                                  unsigned short* __restrict__ Wc,
                                  const int* __restrict__ esrc, const int* __restrict__ edst,
                                  int* __restrict__ degU, int* __restrict__ degI,
                                  int E, int gPrep)
{
  const int b = blockIdx.x;
  if (b >= gPrep){
    int t = (b - gPrep) * 256 + threadIdx.x;
    if (t < E){
      atomicAdd(&degI[edst[t]], 1);
      atomicAdd(&degU[esrc[t]], 1);
    }
    return;
  }
  const int t = b * 256 + threadIdx.x;
  if (t >= 49664) return;
  const unsigned short* Wl = P + P_WL;
  const unsigned short* Wr = P + P_WR;
  const unsigned short* Bm[4] = { Wl, Wr + 16384, Wl + 16384, Wr };
  const unsigned short* Av[4] = { P + P_WPU, P + P_WPU, P + P_WPI, P + P_WPI };
  const unsigned short* bv[4] = { P + P_BPU, P + P_BPU, P + P_BPI, P + P_BPI };
  const unsigned short* bo[4] = { P + P_BL, P + P_BR + 128, P + P_BL + 128, P + P_BR };
  if (t < 49152){
    int job, base;
    if (t < 8192)       { job = 0; base = 0; }
    else if (t < 16384) { job = 1; base = 8192; }
    else if (t < 32768) { job = 2; base = 16384; }
    else                { job = 3; base = 32768; }
    const int local = t - base;
    const int k = local >> 7, n = local & 127;
    const unsigned short* A = Av[job] + (size_t)k * 128;
    const unsigned short* B = Bm[job];
    float s = 0.f;
    #pragma unroll 4
    for (int h = 0; h < 128; h++) s = fmaf(b2f(A[h]), b2f(B[h * 128 + n]), s);
    Wc[t] = f2b(s);
  } else {
    const int local = t - 49152;
    const int job = local >> 7, n = local & 127;
    const unsigned short* B = Bm[job];
    float s = b2f(bo[job][n]);
    for (int h = 0; h < 128; h++) s = fmaf(b2f(bv[job][h]), b2f(B[h * 128 + n]), s);
    Wc[t] = f2b(s);
  }
}

// ---------------- permute+bias  ||  per-block scan  ||  degree histogram — one dispatch
// permute deps: prep; scan/hist deps: count. Disjoint writes, no cross-block deps.
struct PermBiasArgs { const unsigned short* W0[4]; const unsigned short* W1[4];
                      int KS[4]; int base[4]; int n[4];
                      const unsigned short* blo[4]; const unsigned short* bhi[4]; };

__global__ void permute_scanhist_kernel(PermBiasArgs pa, unsigned short* __restrict__ dst,
                                        unsigned short* __restrict__ dstB, int gPerm,
                                        const int* __restrict__ degI, const int* __restrict__ degU,
                                        int* __restrict__ rpI, int* __restrict__ rpU,
                                        int* __restrict__ blkI, int* __restrict__ blkU,
                                        int* __restrict__ histI, int* __restrict__ histU,
                                        int NI, int NU, int BI, int BU, int BI2, int BU2)
{
  const int tid = threadIdx.x;
  const int bk0 = blockIdx.x;
  if (bk0 < gPerm){
    int t = bk0 * 256 + tid;
    if (t >= 114688){
      int u = t - 114688;
      if (u < 1024){
        int set = u >> 8, c = u & 255;
        dstB[u] = (c < 128) ? pa.blo[set][c] : pa.bhi[set][c - 128];
      }
      return;
    }
    int job = 0;
    while (job < 4 && t >= pa.base[job] + pa.n[job]) job++;
    if (job >= 4) return;
    int local = t - pa.base[job];
    int KS = pa.KS[job];
    int j = local & 7, rest = local >> 3;
    int l = rest & 63; rest >>= 6;
    int ks = rest % KS, tile = rest / KS;
    int k = ks * 32 + (l >> 4) * 8 + j;
    int c = tile * 16 + (l & 15);
    dst[t] = (c < 128) ? pa.W0[job][k * 128 + c] : pa.W1[job][k * 128 + (c - 128)];
    return;
  }
  const int b = bk0 - gPerm;
  const int nscan = BI + BU;
  if (b < nscan){
    __shared__ int s[256];
    const int* deg; int* rowptr; int* blksum; int Nd; int bb;
    if (b < BI){ deg = degI; rowptr = rpI; blksum = blkI; Nd = NI; bb = b; }
    else       { deg = degU; rowptr = rpU; blksum = blkU; Nd = NU; bb = b - BI; }
    const int base = bb * 2048 + tid * 8;
    int v[8]; int tot = 0;
    #pragma unroll
    for (int j = 0; j < 8; j++){
      int idx = base + j;
      v[j] = (idx < Nd) ? deg[idx] : 0;
      tot += v[j];
    }
    s[tid] = tot;
    __syncthreads();
    for (int off = 1; off < 256; off <<= 1){
      int add = (tid >= off) ? s[tid - off] : 0;
      __syncthreads();
      s[tid] += add;
      __syncthreads();
    }
    int run = s[tid] - tot;
    #pragma unroll
    for (int j = 0; j < 8; j++){
      int idx = base + j;
      if (idx < Nd) rowptr[idx] = run;
      run += v[j];
    }
    if (tid == 255) blksum[bb] = s[255];
  } else {
    __shared__ int h2[64];
    if (tid < 64) h2[tid] = 0;
    __syncthreads();
    const int bb = b - nscan;
    const int* deg; int* gh; int base; int N;
    if (bb < BI2){ deg = degI; gh = histI; base = bb * 256; N = NI; }
    else         { deg = degU; gh = histU; base = (bb - BI2) * 256; N = NU; }
    const int n = base + tid;
    if (n < N) atomicAdd(&h2[min(deg[n], 63)], 1);
    __syncthreads();
    if (tid < 64 && h2[tid]) atomicAdd(&gh[tid], h2[tid]);
  }
}

// scan_add with LOCAL top-level scan (kills the tops dispatch): each block redundantly
// scans the 64-entry blk array in-wave and picks its own exclusive prefix.
__global__ void scan_add2_kernel(int* __restrict__ rpI, int* __restrict__ rpU,
                                 const int* __restrict__ blkI, const int* __restrict__ blkU,
                                 int* __restrict__ curI, int* __restrict__ curU,
                                 int NI, int NU, int BI, int BU, int E){
  const int b = blockIdx.x;
  int* rowptr; const int* blksum; int* curs; int Nd; int bb; int Bn;
  if (b < BI){ rowptr = rpI; blksum = blkI; curs = curI; Nd = NI; bb = b; Bn = BI; }
  else       { rowptr = rpU; blksum = blkU; curs = curU; Nd = NU; bb = b - BI; Bn = BU; }
  const int tid = threadIdx.x;
  __shared__ int sAdd;
  if (tid < 64){
    int v = (tid < Bn) ? blksum[tid] : 0;
    int x = v;
    #pragma unroll
    for (int off = 1; off < 64; off <<= 1){
      int u = __shfl_up(x, off, 64);
      if (tid >= off) x += u;
    }
    if (tid == bb) sAdd = x - v;     // exclusive prefix at bb
  }
  __syncthreads();
  const int add = sAdd;
  const int base = bb * 2048 + tid * 8;
  #pragma unroll
  for (int j = 0; j < 8; j++){
    int idx = base + j;
    if (idx < Nd){ int v = rowptr[idx] + add; rowptr[idx] = v; curs[idx] = v; }
    else if (idx == Nd) rowptr[idx] = E;
  }
}

// merged scatter: perm placement (LOCAL hist suffix-scan + separate cursor array) + edge scatter
__global__ void scatter_all_kernel(const int* __restrict__ esrc, const int* __restrict__ edst,
                                   int* __restrict__ curI, int* __restrict__ curU,
                                   int* __restrict__ srcI, int* __restrict__ srcU,
                                   const int* __restrict__ rpI, const int* __restrict__ rpU,
                                   const int* __restrict__ histI, const int* __restrict__ histU,
                                   int* __restrict__ hcurI, int* __restrict__ hcurU,
                                   int* __restrict__ permI, int* __restrict__ permU,
                                   int NI, int NU, int E, int BI2, int BU2){
  const int tid = threadIdx.x;
  const int b = blockIdx.x;
  const int BP = BI2 + BU2;
  if (b < BP){
    __shared__ int h[64];
    __shared__ int cur[64];
    if (tid < 64) h[tid] = 0;
    __syncthreads();
    const int* rp; const int* gh; int* ghc; int* perm; int base; int N;
    if (b < BI2){ rp = rpI; gh = histI; ghc = hcurI; perm = permI; base = b * 256; N = NI; }
    else        { rp = rpU; gh = histU; ghc = hcurU; perm = permU; base = (b - BI2) * 256; N = NU; }
    const int n = base + tid;
    int bk = -1;
    if (n < N){ int d = rp[n + 1] - rp[n]; bk = min(d, 63); atomicAdd(&h[bk], 1); }
    __syncthreads();
    if (tid < 64){
      // local suffix-scan of the immutable global hist: start[bk] = #nodes in buckets > bk
      int v = gh[tid];
      int x = v;
      #pragma unroll
      for (int off = 1; off < 64; off <<= 1){
        int u = __shfl_down(x, off, 64);
        x += (tid + off < 64) ? u : 0;
      }
      const int suf = x - v;
      cur[tid] = h[tid] ? (suf + atomicAdd(&ghc[tid], h[tid])) : 0;
    }
    __syncthreads();
    if (n < N){ int r = atomicAdd(&cur[bk], 1); perm[r] = n; }
  } else {
    int t = (b - BP) * 256 + tid;
    if (t < E){
      int d = edst[t];
      int pos = atomicAdd(&curI[d], 1);
      srcI[pos] = esrc[t];
    } else if (t < 2 * E){
      int tt = t - E;
      int d = esrc[tt];
      int pos = atomicAdd(&curU[d], 1);
      srcU[pos] = edst[tt];
    }
  }
}

// ---------------- MFMA linear: 32-row tiles, A-tile staged through LDS (R9-proven)
template<int K>
__device__ __forceinline__ void linear_body(const void* __restrict__ Xv, int xstride,
                                            bool f32,
                                            const unsigned short* __restrict__ Bp,
                                            const unsigned short* __restrict__ bias,
                                            unsigned short* __restrict__ Y, int M, int bx,
                                            unsigned short* __restrict__ lds)
{
  constexpr int KS = K / 32;
  constexpr int LK = K + 8;                  // padded LDS row stride (ushorts)
  constexpr int ROUNDS = (32 * K) / 2048;    // 1 for K=64, 2 for K=128
  const int wave = threadIdx.x >> 6, lane = threadIdx.x & 63;
  const int quad = lane >> 4, l16 = lane & 15;
  const int row0 = bx * 32;

  #pragma unroll
  for (int rd = 0; rd < ROUNDS; rd++){
    const int e = rd * 2048 + (int)threadIdx.x * 8;
    const int rr = e / K, cc = e % K;
    int grow = row0 + rr; if (grow >= M) grow = M - 1;
    unsigned short* dst = lds + rr * LK + cc;
    if (f32){
      const float* p = (const float*)Xv + (size_t)grow * xstride + cc;
      float4 v0 = *(const float4*)p;
      float4 v1 = *(const float4*)(p + 4);
      short8 tmp;
      tmp[0] = (short)f2b(v0.x); tmp[1] = (short)f2b(v0.y);
      tmp[2] = (short)f2b(v0.z); tmp[3] = (short)f2b(v0.w);
      tmp[4] = (short)f2b(v1.x); tmp[5] = (short)f2b(v1.y);
      tmp[6] = (short)f2b(v1.z); tmp[7] = (short)f2b(v1.w);
      *(short8*)dst = tmp;
    } else {
      *(short8*)dst = *(const short8*)((const unsigned short*)Xv + (size_t)grow * xstride + cc);
    }
  }
  __syncthreads();

  float4v acc[2][4];
  const float4v z = {0.f, 0.f, 0.f, 0.f};
  #pragma unroll
  for (int i = 0; i < 2; i++)
    #pragma unroll
    for (int j = 0; j < 4; j++) acc[i][j] = z;

  #pragma unroll
  for (int ks = 0; ks < KS; ks++){
    const int col = ks * 32 + quad * 8;
    short8 a[2];
    #pragma unroll
    for (int mt = 0; mt < 2; mt++)
      a[mt] = *(const short8*)(lds + (mt * 16 + l16) * LK + col);
    short8 b[4];
    #pragma unroll
    for (int ntl = 0; ntl < 4; ntl++){
      const int t = wave * 4 + ntl;
      b[ntl] = *(const short8*)(Bp + ((size_t)(t * KS + ks) * 64 + lane) * 8);
    }
    #pragma unroll
    for (int mt = 0; mt < 2; mt++)
      #pragma unroll
      for (int ntl = 0; ntl < 4; ntl++)
        acc[mt][ntl] = __builtin_amdgcn_mfma_f32_16x16x32_bf16(a[mt], b[ntl], acc[mt][ntl], 0, 0, 0);
  }

  #pragma unroll
  for (int mt = 0; mt < 2; mt++){
    #pragma unroll
    for (int ntl = 0; ntl < 4; ntl++){
      const int t = wave * 4 + ntl;
      const int colb = t * 16 + l16;
      const float bb = b2f(bias[colb]);
      #pragma unroll
      for (int r = 0; r < 4; r++){
        const int row = row0 + mt * 16 + quad * 4 + r;
        if (row < M) Y[(size_t)row * 256 + colb] = f2b(acc[mt][ntl][r] + bb);
      }
    }
  }
}

template<int KA, int KB>
__launch_bounds__(256)
__global__ void linear_both_kernel(const void* __restrict__ XA, int sA,
                                   const unsigned short* __restrict__ BpA,
                                   const unsigned short* __restrict__ biasA,
                                   unsigned short* __restrict__ YA, int MA, int gA,
                                   const void* __restrict__ XB, int sB,
                                   const unsigned short* __restrict__ BpB,
                                   const unsigned short* __restrict__ biasB,
                                   unsigned short* __restrict__ YB, int MB,
                                   const int* __restrict__ flag, int use_flag)
{
  __shared__ unsigned short lds[32 * 136];     // max K=128 padded: 8704 B
  const bool f32 = use_flag && (*flag != 0);
  if ((int)blockIdx.x < gA) linear_body<KA>(XA, sA, f32, BpA, biasA, YA, MA, blockIdx.x, lds);
  else                      linear_body<KB>(XB, sB, f32, BpB, biasB, YB, MB, blockIdx.x - gA, lds);
}

// ================= fused GATv2: 4 nodes/wave (16 lanes each), degree-sorted =================
// R1-exact structure: single online-softmax state, 1 edge/iter, depth-1.5 prefetch, VGPR ~24.
struct GatRel {
  const unsigned short* zlrS; // source features [Ns][256] bf16 (xl at +0)
  const unsigned short* zlrD; // dest features   [Nd][256] bf16 (xr at +128)
  const int* rowptr;
  const int* srcArr;
  const int* perm;            // degree-sorted node ids (descending)
  const unsigned short* att;  // [128]
  const unsigned short* bias; // [128]
  void* out;
  unsigned long long elem_off;
  int Nd;
  int nw;                     // ceil(Nd/4)
};

__launch_bounds__(256)
__global__ void fused_gat_sorted_kernel(GatRel A, GatRel B, int do_relu,
                                        const int* __restrict__ flag, int final_store)
{
  const int wave = threadIdx.x >> 6;
  const int lane = threadIdx.x & 63;
  const int ql = lane & 15;
  const int quad = lane >> 4;
  int gw = blockIdx.x * 4 + wave;
  GatRel R;
  if (gw < A.nw) R = A;
  else {
    gw -= A.nw;
    if (gw >= B.nw) return;
    R = B;
  }

  const int rank = gw * 4 + quad;
  const bool vnode = rank < R.Nd;
  int d = 0;
  if (vnode) d = R.perm[rank];
  int beg = 0, end = 0;
  if (vnode){ beg = R.rowptr[d]; end = R.rowptr[d + 1]; }
  int md = end - beg;
  md = max(md, __shfl_xor(md, 16, 64));
  md = max(md, __shfl_xor(md, 32, 64));

  const uint4* zlS4 = (const uint4*)R.zlrS;
  // xr row of dest node: dims [8*ql, 8*ql+8)
  uint4 rv = ((const uint4*)R.zlrD)[(size_t)d * 32 + 16 + ql];
  float r[8], a[8];
  {
    const unsigned int* rp = (const unsigned int*)&rv;
    #pragma unroll
    for (int j = 0; j < 4; j++){
      r[2*j]   = __uint_as_float(rp[j] << 16);
      r[2*j+1] = __uint_as_float(rp[j] & 0xffff0000u);
    }
  }
  uint4 av = ((const uint4*)R.att)[ql];
  {
    const unsigned int* ap = (const unsigned int*)&av;
    #pragma unroll
    for (int j = 0; j < 4; j++){
      a[2*j]   = __uint_as_float(ap[j] << 16) * LOGSCALE;
      a[2*j+1] = __uint_as_float(ap[j] & 0xffff0000u) * LOGSCALE;
    }
  }

  float m = -1e30f, s = 0.f;
  float acc[8];
  #pragma unroll
  for (int j = 0; j < 8; j++) acc[j] = 0.f;

  if (md > 0){
    const int* sA = R.srcArr;
    int i1 = 0, i2 = 0;
    if (beg < end)     i1 = sA[beg];
    if (beg + 1 < end) i2 = sA[beg + 1];
    uint4 g0 = zlS4[(size_t)i1 * 32 + ql];

    for (int it = 0; it < md; it++){
      uint4 g1 = zlS4[(size_t)i2 * 32 + ql];     // prefetch row for it+1
      int i3 = 0;
      { int ee = beg + it + 2; if (ee < end) i3 = sA[ee]; }   // prefetch idx for it+2
      const bool valid = (beg + it) < end;

      float x[8];
      const unsigned int* gp = (const unsigned int*)&g0;
      #pragma unroll
      for (int j = 0; j < 4; j++){
        x[2*j]   = __uint_as_float(gp[j] << 16);
        x[2*j+1] = __uint_as_float(gp[j] & 0xffff0000u);
      }
      float p = 0.f;
      #pragma unroll
      for (int j = 0; j < 8; j++){
        float t = x[j] + r[j];
        t = fmaxf(t, 0.2f * t);
        p = fmaf(a[j], t, p);
      }
      p = dpp_red8(p);
      const float pv = valid ? p : -1e30f;

      if (__builtin_expect(__any(pv > m + 8.f), 0)){
        const float mn = fmaxf(m, pv);
        const float scO = EXPX(m - mn);
        const float qv = valid ? EXPX(pv - mn) : 0.f;
        s = fmaf(s, scO, qv);
        #pragma unroll
        for (int j = 0; j < 8; j++) acc[j] = fmaf(acc[j], scO, x[j] * qv);
        m = mn;
      } else {
        const float qv = valid ? EXPX(pv - m) : 0.f;
        s += qv;
        #pragma unroll
        for (int j = 0; j < 8; j++) acc[j] = fmaf(x[j], qv, acc[j]);
      }
      g0 = g1; i2 = i3;
    }
  }

  const float inv = 1.f / (s + 1e-16f);
  uint4 bv = ((const uint4*)R.bias)[ql];
  float o[8];
  {
    const unsigned int* bp = (const unsigned int*)&bv;
    #pragma unroll
    for (int j = 0; j < 4; j++){
      o[2*j]   = fmaf(acc[2*j],   inv, __uint_as_float(bp[j] << 16));
      o[2*j+1] = fmaf(acc[2*j+1], inv, __uint_as_float(bp[j] & 0xffff0000u));
    }
  }
  if (do_relu){
    #pragma unroll
    for (int j = 0; j < 8; j++) o[j] = fmaxf(o[j], 0.f);
  }
  if (!vnode) return;
  const size_t eidx = (size_t)R.elem_off + (size_t)d * HDIM + 8 * ql;
  if (final_store && (*flag != 0)){
    float4 f0 = {o[0], o[1], o[2], o[3]};
    float4 f1 = {o[4], o[5], o[6], o[7]};
    float4* op = (float4*)R.out;
    op[eidx >> 2] = f0;
    op[(eidx >> 2) + 1] = f1;
  } else {
    uint4 w;
    unsigned int* wp = (unsigned int*)&w;
    #pragma unroll
    for (int j = 0; j < 4; j++)
      wp[j] = (unsigned int)f2b(o[2*j]) | ((unsigned int)f2b(o[2*j+1]) << 16);
    ((uint4*)R.out)[eidx >> 3] = w;
  }
}

extern "C" void kernel_launch(void* const* d_in, const int* in_sizes, int n_in,
                              void* d_out, int out_size, void* d_ws, size_t ws_size,
                              hipStream_t stream)
{
  const int* esrc = (const int*)d_in[12];
  const int* edst = (const int*)d_in[13];

  const int NU = in_sizes[0] / 64;    // 100000
  const int NI = in_sizes[1] / 128;   // 20000
  const int E  = in_sizes[12];        // 250000
  const size_t fu = (size_t)NU * HDIM, fi = (size_t)NI * HDIM;

  // ---- workspace carve, 256B-aligned regions
  char* w = (char*)d_ws;
  auto carve = [&](size_t bytes){ char* p = w; w += (bytes + 255) & ~(size_t)255; return p; };
  int* flag = (int*)carve(4);
  unsigned short* Wc = (unsigned short*)carve(49664 * 2);
  unsigned short* P  = (unsigned short*)carve((size_t)P_TOT * 2);
  unsigned short* Bp = (unsigned short*)carve(114688 * 2);
  unsigned short* Bc = (unsigned short*)carve(1024 * 2);
  int* rowptrI = (int*)carve(((size_t)NI + 1) * 4);
  int* rowptrU = (int*)carve(((size_t)NU + 1) * 4);
  int* curs    = (int*)carve(((size_t)NI + NU) * 4);
  int* cursI = curs;
  int* cursU = curs + NI;
  int* blkI = (int*)carve(64 * 4);
  int* blkU = (int*)carve(64 * 4);
  int* hists = (int*)carve(256 * 4);       // histI[64] | histU[64] | hcurI[64] | hcurU[64]
  int* histI = hists;
  int* histU = hists + 64;
  int* hcurI = hists + 128;
  int* hcurU = hists + 192;
  int* permI = (int*)carve((size_t)NI * 4);
  int* permU = (int*)carve((size_t)NU * 4);
  int* srcI  = (int*)carve((size_t)E * 4);
  int* srcU  = (int*)carve((size_t)E * 4);
  unsigned short* zlrU = (unsigned short*)carve((size_t)NU * 256 * 2);  // [NU][xl|xr]
  unsigned short* zlrI = (unsigned short*)carve((size_t)NI * 256 * 2);  // [NI][xl|xr]
  (void)ws_size; (void)n_in; (void)out_size; (void)fi;

  unsigned short* stage_zu = (unsigned short*)d_out;          // layer-0 bf16 staging
  unsigned short* stage_zi = (unsigned short*)d_out + fu;
  (void)stage_zi;

  // ---- 1: cvt (+sniff +zero curs/hists/hcur +publish flag)
  CvtArgs ca;
  const int srcIdx[10] = {2, 4, 6, 8, 7, 9, 10, 11, 3, 5};
  const int lens[10] = {8192, 16384, 65536, 65536, 512, 512, 512, 512, 128, 128};
  for (int i = 0; i < 10; i++){ ca.src[i] = d_in[srcIdx[i]]; ca.len[i] = lens[i]; }
  ca.xsniff = (const unsigned short*)d_in[0];
  cvt_all_kernel<<<(P_TOT + 255) / 256, 256, 0, stream>>>(ca, P, flag,
                                                          curs, NI + NU, hists, 256);

  // ---- 2: prep + count (merged; both dep only on cvt)
  const int gPrep = (49664 + 255) / 256;
  const int gCount = (E + 255) / 256;
  prep_count_kernel<<<gPrep + gCount, 256, 0, stream>>>(P, Wc, esrc, edst,
                                                        cursU, cursI, E, gPrep);

  const unsigned short* cWlU0 = Wc;                 // [64,128]
  const unsigned short* cWrU1 = Wc + 8192;          // [64,128]
  const unsigned short* cWlI1 = Wc + 16384;         // [128,128]
  const unsigned short* cWrI0 = Wc + 32768;         // [128,128]

  // ---- 3: permute+bias || scan || hist (merged)
  PermBiasArgs pa;
  pa.W0[0] = cWlU0;                 pa.W1[0] = cWrU1;                 pa.KS[0] = 2; pa.base[0] = 0;     pa.n[0] = 16384;
  pa.W0[1] = cWlI1;                 pa.W1[1] = cWrI0;                 pa.KS[1] = 4; pa.base[1] = 16384; pa.n[1] = 32768;
  pa.W0[2] = P + P_WL + 2 * 16384;  pa.W1[2] = P + P_WR + 3 * 16384;  pa.KS[2] = 4; pa.base[2] = 49152; pa.n[2] = 32768;
  pa.W0[3] = P + P_WL + 3 * 16384;  pa.W1[3] = P + P_WR + 2 * 16384;  pa.KS[3] = 4; pa.base[3] = 81920; pa.n[3] = 32768;
  pa.blo[0] = Wc + 49152;         pa.bhi[0] = Wc + 49152 + 128;
  pa.blo[1] = Wc + 49152 + 256;   pa.bhi[1] = Wc + 49152 + 384;
  pa.blo[2] = P + P_BL + 256;     pa.bhi[2] = P + P_BR + 384;
  pa.blo[3] = P + P_BL + 384;     pa.bhi[3] = P + P_BR + 256;
  const int BI = (NI + 2047) / 2048, BU = (NU + 2047) / 2048;
  const int BI2 = (NI + 255) / 256, BU2 = (NU + 255) / 256;
  const int gPerm = (114688 + 1024 + 255) / 256;
  permute_scanhist_kernel<<<gPerm + BI + BU + BI2 + BU2, 256, 0, stream>>>(
      pa, Bp, Bc, gPerm,
      cursI, cursU, rowptrI, rowptrU, blkI, blkU, histI, histU,
      NI, NU, BI, BU, BI2, BU2);
  unsigned short* BpU0 = Bp;
  unsigned short* BpI0 = Bp + 16384;
  unsigned short* BpU1 = Bp + 49152;
  unsigned short* BpI1 = Bp + 81920;

  // ---- 4: scan_add (local top-scan; tops dispatch eliminated)
  scan_add2_kernel<<<BI + BU, 256, 0, stream>>>(rowptrI, rowptrU, blkI, blkU,
                                                cursI, cursU, NI, NU, BI, BU, E);
  // ---- 5: scatter (perm placement w/ local suffix-scan + edge scatter)
  scatter_all_kernel<<<BI2 + BU2 + (2 * E + 255) / 256, 256, 0, stream>>>(
      esrc, edst, cursI, cursU, srcI, srcU, rowptrI, rowptrU,
      histI, histU, hcurI, hcurU, permI, permU, NI, NU, E, BI2, BU2);

  const int gMU = (NU + 31) / 32, gMI = (NI + 31) / 32;
  const int nwA = (NI + 3) / 4, nwB = (NU + 3) / 4;
  const int gGat = (nwA + nwB + 3) / 4;   // 256-thread blocks = 4 waves

  for (int l = 0; l < 2; l++){
    if (l == 0){
      linear_both_kernel<64, 128><<<gMU + gMI, 256, 0, stream>>>(
          d_in[0], 64, BpU0, Bc, zlrU, NU, gMU,
          d_in[1], 128, BpI0, Bc + 256, zlrI, NI, flag, 1);
    } else {
      linear_both_kernel<128, 128><<<gMU + gMI, 256, 0, stream>>>(
          stage_zu, 128, BpU1, Bc + 512, zlrU, NU, gMU,
          stage_zi, 128, BpI1, Bc + 768, zlrI, NI, flag, 0);
    }
    const int relu = (l == 0);
    const int final_store = (l == 1);

    GatRel A, B;
    // rel 0: user -> item (dst=item)
    A.zlrS = zlrU; A.zlrD = zlrI; A.rowptr = rowptrI; A.srcArr = srcI; A.perm = permI;
    A.att  = P + P_ATT + (l * 2 + 0) * HDIM;
    A.bias = P + P_BIA + (l * 2 + 0) * HDIM;
    A.out = final_store ? d_out : (void*)stage_zu; A.elem_off = fu; A.Nd = NI; A.nw = nwA;
    // rel 1: item -> user (dst=user)
    B.zlrS = zlrI; B.zlrD = zlrU; B.rowptr = rowptrU; B.srcArr = srcU; B.perm = permU;
    B.att  = P + P_ATT + (l * 2 + 1) * HDIM;
    B.bias = P + P_BIA + (l * 2 + 1) * HDIM;
    B.out = final_store ? d_out : (void*)stage_zu; B.elem_off = 0; B.Nd = NU; B.nw = nwB;

    fused_gat_sorted_kernel<<<gGat, 256, 0, stream>>>(A, B, relu, flag, final_store);
  }
}